// Round 2
// baseline (145383.704 us; speedup 1.0000x reference)
//
#include <hip/hip_runtime.h>
#include <hip/hip_cooperative_groups.h>

namespace cg = cooperative_groups;

#define NBLK 256
#define NTHR 256

constexpr int H = 1024, MEL = 80, ATT = 640, TXTD = 640, T = 600, TTXT = 128;
constexpr int G4 = 4096, DIN = H + ATT; // 1664

// ---- workspace layout (floats) ----
constexpr int WS_K     = 0;                  // 128*640
constexpr int WS_V     = WS_K + TTXT * ATT;  // 128*640
constexpr int WS_HBUF  = WS_V + TTXT * ATT;  // 2*1024 (double buffer)
constexpr int WS_C     = WS_HBUF + 2 * H;    // 1024
constexpr int WS_H0BUF = WS_C + H;           // 2*1024
constexpr int WS_C0    = WS_H0BUF + 2 * H;   // 1024
constexpr int WS_H1BUF = WS_C0 + H;          // 2*1024
constexpr int WS_C1    = WS_H1BUF + 2 * H;   // 1024
constexpr int WS_Q     = WS_C1 + H;          // 640
constexpr int WS_W0H   = WS_Q + ATT;         // 4096 (Wih0[:, :1024] @ h)
constexpr int WS_U0    = WS_W0H + G4;        // 4096 (Whh0 @ h0_prev)
constexpr int WS_U1    = WS_U0 + G4;         // 4096 (Whh1 @ h1_prev)
constexpr int WS_CTX   = WS_U1 + G4;         // 640 (unnormalized ctx accum)
constexpr int WS_DEN   = WS_CTX + ATT;       // 1  (softmax denom)
constexpr int WS_GH    = WS_DEN + 1;         // 1  (gate_w[:1024]@h)
constexpr int WS_DEC   = WS_GH + 1;          // 160 (conv output accum)
constexpr int WS_A0    = WS_DEC + 2 * MEL;   // 1024 (tanh(D0w@h1+b))
constexpr int WS_END   = WS_A0 + H;

struct Params {
  const float *residual, *text, *Wih_a, *Whh_a, *bih_a, *bhh_a,
      *Wq, *Wk, *Wv, *v_w, *Wih0, *Whh0, *bih0, *bhh0,
      *Wih1, *Whh1, *bih1, *bhh1, *D0w, *D0b, *D1w, *D1b,
      *conv_w, *conv_b, *gate_w, *gate_b;
  float* out;
  float* ws;
};

__device__ __forceinline__ float sigm(float x) { return 1.0f / (1.0f + __expf(-x)); }
__device__ __forceinline__ float ftanh(float x) {
  x = fminf(15.f, fmaxf(-15.f, x));
  float e = __expf(2.f * x);
  return (e - 1.f) / (e + 1.f);
}

// 64-lane dot of one matrix row with x; n4 = n/4 float4 elements.
// Returns full sum broadcast to all lanes of the wave.
__device__ __forceinline__ float wave_dot(const float* __restrict__ w,
                                          const float* __restrict__ x,
                                          int n4, int lane) {
  float s = 0.f;
  const float4* w4 = (const float4*)w;
  const float4* x4 = (const float4*)x;
  for (int i = lane; i < n4; i += 64) {
    float4 a = w4[i];
    float4 b = x4[i];
    s = fmaf(a.x, b.x, s);
    s = fmaf(a.y, b.y, s);
    s = fmaf(a.z, b.z, s);
    s = fmaf(a.w, b.w, s);
  }
#pragma unroll
  for (int off = 32; off; off >>= 1) s += __shfl_xor(s, off, 64);
  return s;
}

__global__ void __launch_bounds__(NTHR, 1) ar_kernel(Params p) {
  cg::grid_group grid = cg::this_grid();
  const int b = blockIdx.x;
  const int tid = threadIdx.x;
  const int wave = tid >> 6;
  const int lane = tid & 63;

  float* ws = p.ws;
  float* Kw = ws + WS_K;
  float* Vw = ws + WS_V;
  float* hbuf = ws + WS_HBUF;
  float* carr = ws + WS_C;
  float* h0buf = ws + WS_H0BUF;
  float* c0arr = ws + WS_C0;
  float* h1buf = ws + WS_H1BUF;
  float* c1arr = ws + WS_C1;
  float* qv = ws + WS_Q;
  float* w0h = ws + WS_W0H;
  float* u0 = ws + WS_U0;
  float* u1 = ws + WS_U1;
  float* ctxa = ws + WS_CTX;
  float* den = ws + WS_DEN;
  float* ghp = ws + WS_GH;
  float* dec = ws + WS_DEC;
  float* a0 = ws + WS_A0;

  __shared__ __align__(16) float s_out[MEL];
  __shared__ __align__(16) float s_ctx[ATT];
  __shared__ float s_red[4];
  __shared__ float s_d[4];

  // ---------------- init: zero state, precompute K,V ----------------
  if (b == 0) {
    for (int i = tid; i < WS_Q - WS_HBUF; i += NTHR) hbuf[i] = 0.f;  // h,c,h0,c0,h1,c1 (both buffers)
  }
  {
    const int gw = b * 4 + wave;  // 0..1023
    for (int idx = gw; idx < 2 * TTXT * ATT; idx += NBLK * 4) {
      int isV = idx >= TTXT * ATT;
      int rem = isV ? idx - TTXT * ATT : idx;
      int j = rem / ATT;
      int a = rem - j * ATT;
      const float* wrow = (isV ? p.Wv : p.Wk) + a * TXTD;
      float s = wave_dot(wrow, p.text + j * TXTD, TXTD / 4, lane);
      if (lane == 0) (isV ? Vw : Kw)[j * ATT + a] = s;
    }
  }
  grid.sync();

  // ---------------- main sequential loop ----------------
  for (int t = 0; t < T; ++t) {
    const float* h_old = hbuf + (t & 1) * H;
    float* h_new = hbuf + ((t + 1) & 1) * H;
    const float* h0_old = h0buf + (t & 1) * H;
    float* h0_new = h0buf + ((t + 1) & 1) * H;
    const float* h1_old = h1buf + (t & 1) * H;
    float* h1_new = h1buf + ((t + 1) & 1) * H;

    // ---- Phase A: finalize prev output; attn LSTM gates; u0,u1 recurrent matvecs ----
    if (tid < MEL) {
      float o;
      if (t == 0) {
        o = 0.f;
      } else {
        float ls = dec[tid] + p.conv_b[tid];
        float bb = dec[MEL + tid] + p.conv_b[MEL + tid];
        float r = p.residual[(T - t) * MEL + tid];
        o = (r - bb) * __expf(-ls);
        if (b == 0) p.out[(T - t) * MEL + tid] = o;  // total[599-(t-1)]
      }
      s_out[tid] = o;
    }
    __syncthreads();

    {
      const int e = 4 * b + wave;  // h element 0..1023
      float g[4];
#pragma unroll
      for (int k = 0; k < 4; ++k) {
        int row = e + k * H;
        float s = wave_dot(p.Wih_a + row * MEL, s_out, MEL / 4, lane) +
                  wave_dot(p.Whh_a + row * H, h_old, H / 4, lane) +
                  p.bih_a[row] + p.bhh_a[row];
        g[k] = s;
      }
      if (lane == 0) {
        float c2 = sigm(g[1]) * carr[e] + sigm(g[0]) * ftanh(g[2]);
        carr[e] = c2;
        h_new[e] = sigm(g[3]) * ftanh(c2);
      }
#pragma unroll
      for (int k = 0; k < 4; ++k) {
        int row = 16 * b + 4 * wave + k;  // 0..4095
        float s0 = wave_dot(p.Whh0 + row * H, h0_old, H / 4, lane);
        if (lane == 0) u0[row] = s0;
        float s1 = wave_dot(p.Whh1 + row * H, h1_old, H / 4, lane);
        if (lane == 0) u1[row] = s1;
      }
    }
    grid.sync();

    // ---- Phase B: q = Wq@h ; w0h = Wih0[:,:H]@h ; gate h-part ; zero scratch ----
    {
      const int gw = 4 * b + wave;  // 0..1023
      if (gw < ATT) {
        float s = wave_dot(p.Wq + gw * H, h_new, H / 4, lane);
        if (lane == 0) qv[gw] = s;
      }
      if (gw == ATT) {
        float s = wave_dot(p.gate_w, h_new, H / 4, lane);
        if (lane == 0) ghp[0] = s;
      }
#pragma unroll
      for (int k = 0; k < 4; ++k) {
        int row = 4 * gw + k;  // 0..4095
        float s = wave_dot(p.Wih0 + row * DIN, h_new, H / 4, lane);
        if (lane == 0) w0h[row] = s;
      }
      // FIXED: loop-strided scratch zeroing (previous version assumed 1024
      // threads/block; with 256 threads ctxa[256:]/den/dec were never reset).
      if (b == NBLK - 1) {
        for (int i = tid; i < ATT; i += NTHR) ctxa[i] = 0.f;
        if (tid == 0) den[0] = 0.f;
        for (int i = tid; i < 2 * MEL; i += NTHR) dec[i] = 0.f;
      }
    }
    grid.sync();

    // ---- Phase C: scores -> exp -> ctx accumulation (fixed-shift softmax) ----
    if (b < TTXT) {
      const int j = b;
      float sp = 0.f;
      for (int i = tid; i < ATT; i += NTHR)
        sp += ftanh(qv[i] + Kw[j * ATT + i]) * p.v_w[i];
#pragma unroll
      for (int off = 32; off; off >>= 1) sp += __shfl_xor(sp, off, 64);
      if (lane == 0) s_red[wave] = sp;
      __syncthreads();
      float sc = s_red[0] + s_red[1] + s_red[2] + s_red[3];
      float pj = __expf(sc - 16.f);  // scores bounded ~±12, shift is safe
      for (int i = tid; i < ATT; i += NTHR)
        atomicAdd(&ctxa[i], pj * Vw[j * ATT + i]);
      if (tid == 0) atomicAdd(den, pj);
    }
    grid.sync();

    // ---- Phase D: dec LSTM0 (ctx part + staged partials) ; gate output ----
    {
      float inv = 1.f / den[0];
      for (int i = tid; i < ATT; i += NTHR) s_ctx[i] = ctxa[i] * inv;
      __syncthreads();
      const int e = 4 * b + wave;
      float g[4];
#pragma unroll
      for (int k = 0; k < 4; ++k) {
        int row = e + k * H;
        float s = wave_dot(p.Wih0 + row * DIN + H, s_ctx, ATT / 4, lane) +
                  w0h[row] + u0[row] + p.bih0[row] + p.bhh0[row];
        g[k] = s;
      }
      if (lane == 0) {
        float c2 = sigm(g[1]) * c0arr[e] + sigm(g[0]) * ftanh(g[2]);
        c0arr[e] = c2;
        h0_new[e] = sigm(g[3]) * ftanh(c2);
      }
      if (b == 200 && wave == 0) {
        float gc = wave_dot(p.gate_w + H, s_ctx, ATT / 4, lane);
        if (lane == 0) p.out[T * MEL + t] = sigm(ghp[0] + gc + p.gate_b[0]);
      }
    }
    grid.sync();

    // ---- Phase E: dec LSTM1 ----
    {
      const int e = 4 * b + wave;
      float g[4];
#pragma unroll
      for (int k = 0; k < 4; ++k) {
        int row = e + k * H;
        float s = wave_dot(p.Wih1 + row * H, h0_new, H / 4, lane) +
                  u1[row] + p.bih1[row] + p.bhh1[row];
        g[k] = s;
      }
      if (lane == 0) {
        float c2 = sigm(g[1]) * c1arr[e] + sigm(g[0]) * ftanh(g[2]);
        c1arr[e] = c2;
        h1_new[e] = sigm(g[3]) * ftanh(c2);
      }
    }
    grid.sync();

    // ---- Phase F: a0 = tanh(D0w@h1 + D0b) ----
    {
      const int r = 4 * b + wave;
      float s = wave_dot(p.D0w + r * H, h1_new, H / 4, lane) + p.D0b[r];
      if (lane == 0) a0[r] = ftanh(s);
    }
    grid.sync();

    // ---- Phase G: d = tanh(D1w@a0 + D1b) ; conv partial into dec (atomics) ----
    {
      const int r = 4 * b + wave;
      float s = wave_dot(p.D1w + r * H, a0, H / 4, lane) + p.D1b[r];
      if (lane == 0) s_d[wave] = ftanh(s);
      __syncthreads();
      if (tid < 2 * MEL) {
        float acc = 0.f;
#pragma unroll
        for (int w = 0; w < 4; ++w)
          acc += p.conv_w[tid * H + 4 * b + w] * s_d[w];
        atomicAdd(&dec[tid], acc);
      }
    }
    grid.sync();
  }

  // ---- epilogue: output for t = T-1 (total[0]) ----
  if (b == 0 && tid < MEL) {
    float ls = dec[tid] + p.conv_b[tid];
    float bb = dec[MEL + tid] + p.conv_b[MEL + tid];
    float r = p.residual[tid];
    p.out[tid] = (r - bb) * __expf(-ls);
  }
}

extern "C" void kernel_launch(void* const* d_in, const int* in_sizes, int n_in,
                              void* d_out, int out_size, void* d_ws, size_t ws_size,
                              hipStream_t stream) {
  Params hp;
  hp.residual = (const float*)d_in[0];
  hp.text = (const float*)d_in[1];
  hp.Wih_a = (const float*)d_in[2];
  hp.Whh_a = (const float*)d_in[3];
  hp.bih_a = (const float*)d_in[4];
  hp.bhh_a = (const float*)d_in[5];
  hp.Wq = (const float*)d_in[6];
  hp.Wk = (const float*)d_in[7];
  hp.Wv = (const float*)d_in[8];
  hp.v_w = (const float*)d_in[9];
  hp.Wih0 = (const float*)d_in[10];
  hp.Whh0 = (const float*)d_in[11];
  hp.bih0 = (const float*)d_in[12];
  hp.bhh0 = (const float*)d_in[13];
  hp.Wih1 = (const float*)d_in[14];
  hp.Whh1 = (const float*)d_in[15];
  hp.bih1 = (const float*)d_in[16];
  hp.bhh1 = (const float*)d_in[17];
  hp.D0w = (const float*)d_in[18];
  hp.D0b = (const float*)d_in[19];
  hp.D1w = (const float*)d_in[20];
  hp.D1b = (const float*)d_in[21];
  hp.conv_w = (const float*)d_in[22];
  hp.conv_b = (const float*)d_in[23];
  hp.gate_w = (const float*)d_in[24];
  hp.gate_b = (const float*)d_in[25];
  hp.out = (float*)d_out;
  hp.ws = (float*)d_ws;

  void* args[] = {&hp};
  hipLaunchCooperativeKernel((void*)ar_kernel, dim3(NBLK), dim3(NTHR), args, 0,
                             stream);
}

// Round 3
// 127535.718 us; speedup vs baseline: 1.1399x; 1.1399x over previous
//
#include <hip/hip_runtime.h>
#include <hip/hip_cooperative_groups.h>

namespace cg = cooperative_groups;

#define NBLK 256
#define NTHR 1024

constexpr int H = 1024, MEL = 80, ATT = 640, TXTD = 640, T = 600, TTXT = 128;
constexpr int G4 = 4096, DIN = H + ATT; // 1664

// ---- workspace layout (floats) ----
constexpr int WS_K     = 0;                  // 128*640
constexpr int WS_V     = WS_K + TTXT * ATT;  // 128*640
constexpr int WS_HBUF  = WS_V + TTXT * ATT;  // 2*1024 (double buffer)
constexpr int WS_C     = WS_HBUF + 2 * H;    // 1024
constexpr int WS_H0BUF = WS_C + H;           // 2*1024
constexpr int WS_C0    = WS_H0BUF + 2 * H;   // 1024
constexpr int WS_H1BUF = WS_C0 + H;          // 2*1024
constexpr int WS_C1    = WS_H1BUF + 2 * H;   // 1024
constexpr int WS_Q     = WS_C1 + H;          // 640
constexpr int WS_W0H   = WS_Q + ATT;         // 4096 (Wih0[:, :1024] @ h)
constexpr int WS_U0    = WS_W0H + G4;        // 4096 (Whh0 @ h0_prev)
constexpr int WS_U1    = WS_U0 + G4;         // 4096 (Whh1 @ h1_prev)
constexpr int WS_CTX   = WS_U1 + G4;         // 640 (unnormalized ctx accum)
constexpr int WS_DEN   = WS_CTX + ATT;       // 1  (softmax denom)
constexpr int WS_GH    = WS_DEN + 1;         // 1  (gate_w[:1024]@h)
constexpr int WS_DEC   = WS_GH + 1;          // 160 (conv output accum)
constexpr int WS_A0    = WS_DEC + 2 * MEL;   // 1024 (tanh(D0w@h1+b))
constexpr int WS_END   = WS_A0 + H;

struct Params {
  const float *residual, *text, *Wih_a, *Whh_a, *bih_a, *bhh_a,
      *Wq, *Wk, *Wv, *v_w, *Wih0, *Whh0, *bih0, *bhh0,
      *Wih1, *Whh1, *bih1, *bhh1, *D0w, *D0b, *D1w, *D1b,
      *conv_w, *conv_b, *gate_w, *gate_b;
  float* out;
  float* ws;
};

__device__ __forceinline__ float sigm(float x) { return 1.0f / (1.0f + __expf(-x)); }
__device__ __forceinline__ float ftanh(float x) {
  x = fminf(15.f, fmaxf(-15.f, x));
  float e = __expf(2.f * x);
  return (e - 1.f) / (e + 1.f);
}

// N interleaved 64-lane row-dots (per-row weight AND x pointers). All loads of
// all N rows are issued before the reduces -> N*ceil(n4/64) loads in flight.
template <int N>
__device__ __forceinline__ void wave_dotN(const float* const (&w)[N],
                                          const float* const (&x)[N], int n4,
                                          int lane, float (&out)[N]) {
#pragma unroll
  for (int j = 0; j < N; ++j) out[j] = 0.f;
  for (int i = lane; i < n4; i += 64) {
#pragma unroll
    for (int j = 0; j < N; ++j) {
      float4 a = ((const float4*)w[j])[i];
      float4 b = ((const float4*)x[j])[i];
      out[j] = fmaf(a.x, b.x, out[j]);
      out[j] = fmaf(a.y, b.y, out[j]);
      out[j] = fmaf(a.z, b.z, out[j]);
      out[j] = fmaf(a.w, b.w, out[j]);
    }
  }
#pragma unroll
  for (int j = 0; j < N; ++j) {
#pragma unroll
    for (int off = 32; off; off >>= 1) out[j] += __shfl_xor(out[j], off, 64);
  }
}

__device__ __forceinline__ float wave_dot(const float* __restrict__ w,
                                          const float* __restrict__ x,
                                          int n4, int lane) {
  float s = 0.f;
  const float4* w4 = (const float4*)w;
  const float4* x4 = (const float4*)x;
  for (int i = lane; i < n4; i += 64) {
    float4 a = w4[i];
    float4 b = x4[i];
    s = fmaf(a.x, b.x, s);
    s = fmaf(a.y, b.y, s);
    s = fmaf(a.z, b.z, s);
    s = fmaf(a.w, b.w, s);
  }
#pragma unroll
  for (int off = 32; off; off >>= 1) s += __shfl_xor(s, off, 64);
  return s;
}

__global__ void __launch_bounds__(NTHR, 4) ar_kernel(Params p) {
  cg::grid_group grid = cg::this_grid();
  const int b = blockIdx.x;
  const int tid = threadIdx.x;
  const int wave = tid >> 6;   // 0..15
  const int lane = tid & 63;
  const int sg = wave >> 2;    // element subgroup 0..3
  const int wg = wave & 3;     // gate / k-chunk within subgroup
  const int gw = b * 16 + wave;  // global wave 0..4095

  float* ws = p.ws;
  float* Kw = ws + WS_K;
  float* Vw = ws + WS_V;
  float* hbuf = ws + WS_HBUF;
  float* carr = ws + WS_C;
  float* h0buf = ws + WS_H0BUF;
  float* c0arr = ws + WS_C0;
  float* h1buf = ws + WS_H1BUF;
  float* c1arr = ws + WS_C1;
  float* qv = ws + WS_Q;
  float* w0h = ws + WS_W0H;
  float* u0 = ws + WS_U0;
  float* u1 = ws + WS_U1;
  float* ctxa = ws + WS_CTX;
  float* den = ws + WS_DEN;
  float* ghp = ws + WS_GH;
  float* dec = ws + WS_DEC;
  float* a0 = ws + WS_A0;

  __shared__ __align__(16) float s_out[MEL];
  __shared__ __align__(16) float s_ctx[ATT];
  __shared__ float s_red[16];
  __shared__ float s_d[4];

  // ---------------- init: zero state, precompute K,V ----------------
  if (b == 0) {
    for (int i = tid; i < 9 * H; i += NTHR) hbuf[i] = 0.f;  // h,c,h0,c0,h1,c1
  }
  for (int idx = gw; idx < 2 * TTXT * ATT; idx += NBLK * 16) {
    int isV = idx >= TTXT * ATT;
    int rem = isV ? idx - TTXT * ATT : idx;
    int j = rem / ATT;
    int a = rem - j * ATT;
    const float* wrow = (isV ? p.Wv : p.Wk) + a * TXTD;
    float s = wave_dot(wrow, p.text + j * TXTD, TXTD / 4, lane);
    if (lane == 0) (isV ? Vw : Kw)[j * ATT + a] = s;
  }
  grid.sync();

  // ---------------- main sequential loop ----------------
  for (int t = 0; t < T; ++t) {
    const float* h_old = hbuf + (t & 1) * H;
    float* h_new = hbuf + ((t + 1) & 1) * H;
    const float* h0_old = h0buf + (t & 1) * H;
    float* h0_new = h0buf + ((t + 1) & 1) * H;
    const float* h1_old = h1buf + (t & 1) * H;
    float* h1_new = h1buf + ((t + 1) & 1) * H;

    // ---- Phase A: prev output; attn-LSTM gate row + u0/u1 rows per wave ----
    if (tid < MEL) {
      float o;
      if (t == 0) {
        o = 0.f;
      } else {
        float ls = dec[tid] + p.conv_b[tid];
        float bb = dec[MEL + tid] + p.conv_b[MEL + tid];
        float r = p.residual[(T - t) * MEL + tid];
        o = (r - bb) * __expf(-ls);
        if (b == 0) p.out[(T - t) * MEL + tid] = o;
      }
      s_out[tid] = o;
    }
    __syncthreads();

    {
      const int e = 4 * b + sg;
      const int grow = e + wg * H;  // attn-LSTM gate row
      const float* wk[3] = {p.Whh_a + (size_t)grow * H,
                            p.Whh0 + (size_t)gw * H,
                            p.Whh1 + (size_t)gw * H};
      const float* xs[3] = {h_old, h0_old, h1_old};
      float s3[3];
      wave_dotN<3>(wk, xs, H / 4, lane, s3);
      float sm = wave_dot(p.Wih_a + (size_t)grow * MEL, s_out, MEL / 4, lane);
      if (lane == 0) {
        u0[gw] = s3[1];
        u1[gw] = s3[2];
        s_red[wave] = s3[0] + sm + p.bih_a[grow] + p.bhh_a[grow];
      }
      __syncthreads();
      if (tid < 4) {
        int ee = 4 * b + tid;
        float gi = s_red[tid * 4 + 0], gf = s_red[tid * 4 + 1];
        float gg = s_red[tid * 4 + 2], go = s_red[tid * 4 + 3];
        float c2 = sigm(gf) * carr[ee] + sigm(gi) * ftanh(gg);
        carr[ee] = c2;
        h_new[ee] = sigm(go) * ftanh(c2);
      }
    }
    grid.sync();

    // ---- Phase B: w0h row per wave (+Wq/gate for low waves); zero scratch ----
    {
      const float* wr0 = p.Wih0 + (size_t)gw * DIN;
      if (gw < ATT) {
        const float* wk[2] = {wr0, p.Wq + (size_t)gw * H};
        const float* xs[2] = {h_new, h_new};
        float s2[2];
        wave_dotN<2>(wk, xs, H / 4, lane, s2);
        if (lane == 0) {
          w0h[gw] = s2[0];
          qv[gw] = s2[1];
        }
      } else if (gw == ATT) {
        const float* wk[2] = {wr0, p.gate_w};
        const float* xs[2] = {h_new, h_new};
        float s2[2];
        wave_dotN<2>(wk, xs, H / 4, lane, s2);
        if (lane == 0) {
          w0h[gw] = s2[0];
          ghp[0] = s2[1];
        }
      } else {
        float s = wave_dot(wr0, h_new, H / 4, lane);
        if (lane == 0) w0h[gw] = s;
      }
      if (b == NBLK - 1) {
        for (int i = tid; i < ATT; i += NTHR) ctxa[i] = 0.f;
        if (tid == 0) den[0] = 0.f;
        for (int i = tid; i < 2 * MEL; i += NTHR) dec[i] = 0.f;
      }
    }
    grid.sync();

    // ---- Phase C: scores -> exp -> ctx accumulation (fixed-shift softmax) ----
    if (b < TTXT) {
      const int j = b;
      float sp = 0.f;
      for (int i = tid; i < ATT; i += NTHR)
        sp += ftanh(qv[i] + Kw[j * ATT + i]) * p.v_w[i];
#pragma unroll
      for (int off = 32; off; off >>= 1) sp += __shfl_xor(sp, off, 64);
      if (lane == 0) s_red[wave] = sp;
      __syncthreads();
      float sc = 0.f;
#pragma unroll
      for (int k = 0; k < 16; ++k) sc += s_red[k];
      float pj = __expf(sc - 16.f);  // scores bounded ~±11, shift is safe
      for (int i = tid; i < ATT; i += NTHR)
        atomicAdd(&ctxa[i], pj * Vw[j * ATT + i]);
      if (tid == 0) atomicAdd(den, pj);
    }
    grid.sync();

    // ---- Phase D: dec LSTM0: one ctx-part row per wave; LDS combine ----
    {
      float inv = 1.f / den[0];
      for (int i = tid; i < ATT; i += NTHR) s_ctx[i] = ctxa[i] * inv;
      __syncthreads();
      const int e = 4 * b + sg;
      const int row = e + wg * H;
      float s = wave_dot(p.Wih0 + (size_t)row * DIN + H, s_ctx, ATT / 4, lane);
      if (lane == 0)
        s_red[wave] = s + w0h[row] + u0[row] + p.bih0[row] + p.bhh0[row];
      if (b == 0 && wave == 15) {
        float gc = wave_dot(p.gate_w + H, s_ctx, ATT / 4, lane);
        if (lane == 0) p.out[T * MEL + t] = sigm(ghp[0] + gc + p.gate_b[0]);
      }
      __syncthreads();
      if (tid < 4) {
        int ee = 4 * b + tid;
        float gi = s_red[tid * 4 + 0], gf = s_red[tid * 4 + 1];
        float gg = s_red[tid * 4 + 2], go = s_red[tid * 4 + 3];
        float c2 = sigm(gf) * c0arr[ee] + sigm(gi) * ftanh(gg);
        c0arr[ee] = c2;
        h0_new[ee] = sigm(go) * ftanh(c2);
      }
    }
    grid.sync();

    // ---- Phase E: dec LSTM1: one row per wave; LDS combine ----
    {
      const int e = 4 * b + sg;
      const int row = e + wg * H;
      float s = wave_dot(p.Wih1 + (size_t)row * H, h0_new, H / 4, lane);
      if (lane == 0)
        s_red[wave] = s + u1[row] + p.bih1[row] + p.bhh1[row];
      __syncthreads();
      if (tid < 4) {
        int ee = 4 * b + tid;
        float gi = s_red[tid * 4 + 0], gf = s_red[tid * 4 + 1];
        float gg = s_red[tid * 4 + 2], go = s_red[tid * 4 + 3];
        float c2 = sigm(gf) * c1arr[ee] + sigm(gi) * ftanh(gg);
        c1arr[ee] = c2;
        h1_new[ee] = sigm(go) * ftanh(c2);
      }
    }
    grid.sync();

    // ---- Phase F: a0 = tanh(D0w@h1 + D0b); rows 4b..4b+3, k-split 4 waves ----
    {
      const int r = 4 * b + sg;
      float4 a = ((const float4*)(p.D0w + (size_t)r * H))[wg * 64 + lane];
      float4 x = ((const float4*)h1_new)[wg * 64 + lane];
      float s = a.x * x.x + a.y * x.y + a.z * x.z + a.w * x.w;
#pragma unroll
      for (int off = 32; off; off >>= 1) s += __shfl_xor(s, off, 64);
      if (lane == 0) s_red[wave] = s;
      __syncthreads();
      if (tid < 4) {
        int r2 = 4 * b + tid;
        float tot = s_red[tid * 4] + s_red[tid * 4 + 1] + s_red[tid * 4 + 2] +
                    s_red[tid * 4 + 3];
        a0[r2] = ftanh(tot + p.D0b[r2]);
      }
    }
    grid.sync();

    // ---- Phase G: d = tanh(D1w@a0 + D1b); conv partial into dec ----
    {
      const int r = 4 * b + sg;
      float4 a = ((const float4*)(p.D1w + (size_t)r * H))[wg * 64 + lane];
      float4 x = ((const float4*)a0)[wg * 64 + lane];
      float s = a.x * x.x + a.y * x.y + a.z * x.z + a.w * x.w;
#pragma unroll
      for (int off = 32; off; off >>= 1) s += __shfl_xor(s, off, 64);
      if (lane == 0) s_red[wave] = s;
      __syncthreads();
      if (tid < 4) {
        int r2 = 4 * b + tid;
        float tot = s_red[tid * 4] + s_red[tid * 4 + 1] + s_red[tid * 4 + 2] +
                    s_red[tid * 4 + 3];
        s_d[tid] = ftanh(tot + p.D1b[r2]);
      }
      __syncthreads();
      if (tid < 2 * MEL) {
        float acc = 0.f;
#pragma unroll
        for (int w = 0; w < 4; ++w)
          acc += p.conv_w[tid * H + 4 * b + w] * s_d[w];
        atomicAdd(&dec[tid], acc);
      }
    }
    grid.sync();
  }

  // ---- epilogue: output for t = T-1 (total[0]) ----
  if (b == 0 && tid < MEL) {
    float ls = dec[tid] + p.conv_b[tid];
    float bb = dec[MEL + tid] + p.conv_b[MEL + tid];
    float r = p.residual[tid];
    p.out[tid] = (r - bb) * __expf(-ls);
  }
}

extern "C" void kernel_launch(void* const* d_in, const int* in_sizes, int n_in,
                              void* d_out, int out_size, void* d_ws, size_t ws_size,
                              hipStream_t stream) {
  Params hp;
  hp.residual = (const float*)d_in[0];
  hp.text = (const float*)d_in[1];
  hp.Wih_a = (const float*)d_in[2];
  hp.Whh_a = (const float*)d_in[3];
  hp.bih_a = (const float*)d_in[4];
  hp.bhh_a = (const float*)d_in[5];
  hp.Wq = (const float*)d_in[6];
  hp.Wk = (const float*)d_in[7];
  hp.Wv = (const float*)d_in[8];
  hp.v_w = (const float*)d_in[9];
  hp.Wih0 = (const float*)d_in[10];
  hp.Whh0 = (const float*)d_in[11];
  hp.bih0 = (const float*)d_in[12];
  hp.bhh0 = (const float*)d_in[13];
  hp.Wih1 = (const float*)d_in[14];
  hp.Whh1 = (const float*)d_in[15];
  hp.bih1 = (const float*)d_in[16];
  hp.bhh1 = (const float*)d_in[17];
  hp.D0w = (const float*)d_in[18];
  hp.D0b = (const float*)d_in[19];
  hp.D1w = (const float*)d_in[20];
  hp.D1b = (const float*)d_in[21];
  hp.conv_w = (const float*)d_in[22];
  hp.conv_b = (const float*)d_in[23];
  hp.gate_w = (const float*)d_in[24];
  hp.gate_b = (const float*)d_in[25];
  hp.out = (float*)d_out;
  hp.ws = (float*)d_ws;

  void* args[] = {&hp};
  hipLaunchCooperativeKernel((void*)ar_kernel, dim3(NBLK), dim3(NTHR), args, 0,
                             stream);
}

// Round 4
// 89481.451 us; speedup vs baseline: 1.6247x; 1.4253x over previous
//
#include <hip/hip_runtime.h>

#define NBLK 256
#define NTHR 1024

constexpr int H = 1024, MEL = 80, ATT = 640, TXTD = 640, T = 600, TTXT = 128;
constexpr int G4 = 4096, DIN = H + ATT; // 1664

// ---- workspace layout (floats) ----
constexpr int WS_K     = 0;                  // 128*640
constexpr int WS_V     = WS_K + TTXT * ATT;  // 128*640
constexpr int WS_HBUF  = WS_V + TTXT * ATT;  // 2*1024 (double buffer)
constexpr int WS_C     = WS_HBUF + 2 * H;    // 1024
constexpr int WS_H0BUF = WS_C + H;           // 2*1024
constexpr int WS_C0    = WS_H0BUF + 2 * H;   // 1024
constexpr int WS_H1BUF = WS_C0 + H;          // 2*1024
constexpr int WS_C1    = WS_H1BUF + 2 * H;   // 1024
constexpr int WS_Q     = WS_C1 + H;          // 640
constexpr int WS_W0H   = WS_Q + ATT;         // 4096 (Wih0[:, :1024] @ h)
constexpr int WS_U0    = WS_W0H + G4;        // 4096 (Whh0 @ h0_prev)
constexpr int WS_U1    = WS_U0 + G4;         // 4096 (Whh1 @ h1_prev)
constexpr int WS_CTX   = WS_U1 + G4;         // 640 (unnormalized ctx accum)
constexpr int WS_DEN   = WS_CTX + ATT;       // 1  (softmax denom)
constexpr int WS_GH    = WS_DEN + 1;         // 1  (gate_w[:1024]@h)
constexpr int WS_DEC   = WS_GH + 1;          // 160 (conv output accum)
constexpr int WS_A0    = WS_DEC + 2 * MEL;   // 1024 (tanh(D0w@h1+b))
constexpr int WS_END   = WS_A0 + H;
constexpr int WS_BAR   = (WS_END + 63) & ~63;  // barrier counter (aligned)

struct Params {
  const float *residual, *text, *Wih_a, *Whh_a, *bih_a, *bhh_a,
      *Wq, *Wk, *Wv, *v_w, *Wih0, *Whh0, *bih0, *bhh0,
      *Wih1, *Whh1, *bih1, *bhh1, *D0w, *D0b, *D1w, *D1b,
      *conv_w, *conv_b, *gate_w, *gate_b;
  float* out;
  float* ws;
};

__device__ __forceinline__ float sigm(float x) { return 1.0f / (1.0f + __expf(-x)); }
__device__ __forceinline__ float ftanh(float x) {
  x = fminf(15.f, fmaxf(-15.f, x));
  float e = __expf(2.f * x);
  return (e - 1.f) / (e + 1.f);
}

// Fast grid barrier: one relaxed agent-scope atomicAdd per block + relaxed
// spin; __threadfence() provides release/acquire (L2 wb/inv on gfx950).
// cnt monotonically increases; barrier k complete when cnt >= (k+1)*NBLK.
__device__ __forceinline__ void gbar(unsigned* cnt) {
  __syncthreads();
  if (threadIdx.x == 0) {
    __threadfence();  // release: my block's ws stores -> device visible
    unsigned g = __hip_atomic_fetch_add(cnt, 1u, __ATOMIC_RELAXED,
                                        __HIP_MEMORY_SCOPE_AGENT);
    unsigned target = (g / NBLK + 1u) * NBLK;
    while (__hip_atomic_load(cnt, __ATOMIC_RELAXED,
                             __HIP_MEMORY_SCOPE_AGENT) < target)
      __builtin_amdgcn_s_sleep(1);
    __threadfence();  // acquire: invalidate stale L1/L2 lines
  }
  __syncthreads();
}

// N row-dots of length-1024 rows; all 8 float4 loads per row batched before
// the FMAs so the memory pipe has them in flight together.
template <int N>
__device__ __forceinline__ void dotrows1024(const float* const (&w)[N],
                                            const float* const (&x)[N],
                                            int lane, float (&out)[N]) {
#pragma unroll
  for (int j = 0; j < N; ++j) {
    const float4* w4 = (const float4*)w[j];
    const float4* x4 = (const float4*)x[j];
    float4 a0 = w4[lane], a1 = w4[lane + 64], a2 = w4[lane + 128],
           a3 = w4[lane + 192];
    float4 b0 = x4[lane], b1 = x4[lane + 64], b2 = x4[lane + 128],
           b3 = x4[lane + 192];
    float s0 = a0.x * b0.x, s1 = a1.x * b1.x;
    s0 = fmaf(a0.y, b0.y, s0); s1 = fmaf(a1.y, b1.y, s1);
    s0 = fmaf(a0.z, b0.z, s0); s1 = fmaf(a1.z, b1.z, s1);
    s0 = fmaf(a0.w, b0.w, s0); s1 = fmaf(a1.w, b1.w, s1);
    s0 = fmaf(a2.x, b2.x, s0); s1 = fmaf(a3.x, b3.x, s1);
    s0 = fmaf(a2.y, b2.y, s0); s1 = fmaf(a3.y, b3.y, s1);
    s0 = fmaf(a2.z, b2.z, s0); s1 = fmaf(a3.z, b3.z, s1);
    s0 = fmaf(a2.w, b2.w, s0); s1 = fmaf(a3.w, b3.w, s1);
    out[j] = s0 + s1;
  }
#pragma unroll
  for (int j = 0; j < N; ++j) {
#pragma unroll
    for (int off = 32; off; off >>= 1) out[j] += __shfl_xor(out[j], off, 64);
  }
}

__device__ __forceinline__ float wave_dot(const float* __restrict__ w,
                                          const float* __restrict__ x,
                                          int n4, int lane) {
  float s = 0.f;
  const float4* w4 = (const float4*)w;
  const float4* x4 = (const float4*)x;
  for (int i = lane; i < n4; i += 64) {
    float4 a = w4[i];
    float4 b = x4[i];
    s = fmaf(a.x, b.x, s);
    s = fmaf(a.y, b.y, s);
    s = fmaf(a.z, b.z, s);
    s = fmaf(a.w, b.w, s);
  }
#pragma unroll
  for (int off = 32; off; off >>= 1) s += __shfl_xor(s, off, 64);
  return s;
}

__global__ void __launch_bounds__(NTHR, 4) ar_kernel(Params p) {
  const int b = blockIdx.x;
  const int tid = threadIdx.x;
  const int wave = tid >> 6;   // 0..15
  const int lane = tid & 63;
  const int sg = wave >> 2;    // element subgroup 0..3
  const int wg = wave & 3;     // gate / k-chunk within subgroup
  const int gw = b * 16 + wave;  // global wave 0..4095

  float* ws = p.ws;
  float* Kw = ws + WS_K;
  float* Vw = ws + WS_V;
  float* hbuf = ws + WS_HBUF;
  float* carr = ws + WS_C;
  float* h0buf = ws + WS_H0BUF;
  float* c0arr = ws + WS_C0;
  float* h1buf = ws + WS_H1BUF;
  float* c1arr = ws + WS_C1;
  float* qv = ws + WS_Q;
  float* w0h = ws + WS_W0H;
  float* u0 = ws + WS_U0;
  float* u1 = ws + WS_U1;
  float* ctxa = ws + WS_CTX;
  float* den = ws + WS_DEN;
  float* ghp = ws + WS_GH;
  float* dec = ws + WS_DEC;
  float* a0 = ws + WS_A0;
  unsigned* bar = (unsigned*)(ws + WS_BAR);

  __shared__ __align__(16) float s_out[MEL];
  __shared__ __align__(16) float s_ctx[ATT];
  __shared__ float s_red[16];
  __shared__ float s_d[4];

  // ---------------- init: zero state, precompute K,V ----------------
  if (b == 0) {
    for (int i = tid; i < 9 * H; i += NTHR) hbuf[i] = 0.f;  // h,c,h0,c0,h1,c1
  }
  for (int idx = gw; idx < 2 * TTXT * ATT; idx += NBLK * 16) {
    int isV = idx >= TTXT * ATT;
    int rem = isV ? idx - TTXT * ATT : idx;
    int j = rem / ATT;
    int a = rem - j * ATT;
    const float* wrow = (isV ? p.Wv : p.Wk) + a * TXTD;
    float s = wave_dot(wrow, p.text + j * TXTD, TXTD / 4, lane);
    if (lane == 0) (isV ? Vw : Kw)[j * ATT + a] = s;
  }
  gbar(bar);

  // ---------------- main sequential loop ----------------
  for (int t = 0; t < T; ++t) {
    const float* h_old = hbuf + (t & 1) * H;
    float* h_new = hbuf + ((t + 1) & 1) * H;
    const float* h0_old = h0buf + (t & 1) * H;
    float* h0_new = h0buf + ((t + 1) & 1) * H;
    const float* h1_old = h1buf + (t & 1) * H;
    float* h1_new = h1buf + ((t + 1) & 1) * H;

    // ---- Phase A: prev output; attn-LSTM gate row + u0/u1 rows per wave ----
    if (tid < MEL) {
      float o;
      if (t == 0) {
        o = 0.f;
      } else {
        float ls = dec[tid] + p.conv_b[tid];
        float bb = dec[MEL + tid] + p.conv_b[MEL + tid];
        float r = p.residual[(T - t) * MEL + tid];
        o = (r - bb) * __expf(-ls);
        if (b == 0) p.out[(T - t) * MEL + tid] = o;
      }
      s_out[tid] = o;
    }
    __syncthreads();

    {
      const int e = 4 * b + sg;
      const int grow = e + wg * H;  // attn-LSTM gate row
      const float* wk[3] = {p.Whh_a + (size_t)grow * H,
                            p.Whh0 + (size_t)gw * H,
                            p.Whh1 + (size_t)gw * H};
      const float* xs[3] = {h_old, h0_old, h1_old};
      float s3[3];
      dotrows1024<3>(wk, xs, lane, s3);
      float sm = wave_dot(p.Wih_a + (size_t)grow * MEL, s_out, MEL / 4, lane);
      if (lane == 0) {
        u0[gw] = s3[1];
        u1[gw] = s3[2];
        s_red[wave] = s3[0] + sm + p.bih_a[grow] + p.bhh_a[grow];
      }
      __syncthreads();
      if (tid < 4) {
        int ee = 4 * b + tid;
        float gi = s_red[tid * 4 + 0], gf = s_red[tid * 4 + 1];
        float gg = s_red[tid * 4 + 2], go = s_red[tid * 4 + 3];
        float c2 = sigm(gf) * carr[ee] + sigm(gi) * ftanh(gg);
        carr[ee] = c2;
        h_new[ee] = sigm(go) * ftanh(c2);
      }
    }
    gbar(bar);

    // ---- Phase B: w0h row per wave (+Wq/gate for low waves); zero scratch ----
    {
      const float* wr0 = p.Wih0 + (size_t)gw * DIN;
      if (gw < ATT) {
        const float* wk[2] = {wr0, p.Wq + (size_t)gw * H};
        const float* xs[2] = {h_new, h_new};
        float s2[2];
        dotrows1024<2>(wk, xs, lane, s2);
        if (lane == 0) {
          w0h[gw] = s2[0];
          qv[gw] = s2[1];
        }
      } else if (gw == ATT) {
        const float* wk[2] = {wr0, p.gate_w};
        const float* xs[2] = {h_new, h_new};
        float s2[2];
        dotrows1024<2>(wk, xs, lane, s2);
        if (lane == 0) {
          w0h[gw] = s2[0];
          ghp[0] = s2[1];
        }
      } else {
        const float* wk[1] = {wr0};
        const float* xs[1] = {h_new};
        float s1[1];
        dotrows1024<1>(wk, xs, lane, s1);
        if (lane == 0) w0h[gw] = s1[0];
      }
      if (b == NBLK - 1) {
        for (int i = tid; i < ATT; i += NTHR) ctxa[i] = 0.f;
        if (tid == 0) den[0] = 0.f;
        for (int i = tid; i < 2 * MEL; i += NTHR) dec[i] = 0.f;
      }
    }
    gbar(bar);

    // ---- Phase C: scores -> exp -> ctx accumulation (fixed-shift softmax) ----
    if (b < TTXT) {
      const int j = b;
      float sp = 0.f;
      for (int i = tid; i < ATT; i += NTHR)
        sp += ftanh(qv[i] + Kw[j * ATT + i]) * p.v_w[i];
#pragma unroll
      for (int off = 32; off; off >>= 1) sp += __shfl_xor(sp, off, 64);
      if (lane == 0) s_red[wave] = sp;
      __syncthreads();
      float sc = 0.f;
#pragma unroll
      for (int k = 0; k < 16; ++k) sc += s_red[k];
      float pj = __expf(sc - 16.f);  // scores bounded ~±11, shift is safe
      for (int i = tid; i < ATT; i += NTHR)
        atomicAdd(&ctxa[i], pj * Vw[j * ATT + i]);
      if (tid == 0) atomicAdd(den, pj);
    }
    gbar(bar);

    // ---- Phase D: dec LSTM0: one ctx-part row per wave; LDS combine ----
    {
      float inv = 1.f / den[0];
      for (int i = tid; i < ATT; i += NTHR) s_ctx[i] = ctxa[i] * inv;
      __syncthreads();
      const int e = 4 * b + sg;
      const int row = e + wg * H;
      float s = wave_dot(p.Wih0 + (size_t)row * DIN + H, s_ctx, ATT / 4, lane);
      if (lane == 0)
        s_red[wave] = s + w0h[row] + u0[row] + p.bih0[row] + p.bhh0[row];
      if (b == 0 && wave == 15) {
        float gc = wave_dot(p.gate_w + H, s_ctx, ATT / 4, lane);
        if (lane == 0) p.out[T * MEL + t] = sigm(ghp[0] + gc + p.gate_b[0]);
      }
      __syncthreads();
      if (tid < 4) {
        int ee = 4 * b + tid;
        float gi = s_red[tid * 4 + 0], gf = s_red[tid * 4 + 1];
        float gg = s_red[tid * 4 + 2], go = s_red[tid * 4 + 3];
        float c2 = sigm(gf) * c0arr[ee] + sigm(gi) * ftanh(gg);
        c0arr[ee] = c2;
        h0_new[ee] = sigm(go) * ftanh(c2);
      }
    }
    gbar(bar);

    // ---- Phase E: dec LSTM1: one row per wave; LDS combine ----
    {
      const int e = 4 * b + sg;
      const int row = e + wg * H;
      const float* wk[1] = {p.Wih1 + (size_t)row * H};
      const float* xs[1] = {h0_new};
      float s1[1];
      dotrows1024<1>(wk, xs, lane, s1);
      if (lane == 0)
        s_red[wave] = s1[0] + u1[row] + p.bih1[row] + p.bhh1[row];
      __syncthreads();
      if (tid < 4) {
        int ee = 4 * b + tid;
        float gi = s_red[tid * 4 + 0], gf = s_red[tid * 4 + 1];
        float gg = s_red[tid * 4 + 2], go = s_red[tid * 4 + 3];
        float c2 = sigm(gf) * c1arr[ee] + sigm(gi) * ftanh(gg);
        c1arr[ee] = c2;
        h1_new[ee] = sigm(go) * ftanh(c2);
      }
    }
    gbar(bar);

    // ---- Phase F: a0 = tanh(D0w@h1 + D0b); rows 4b..4b+3, k-split 4 waves ----
    {
      const int r = 4 * b + sg;
      float4 a = ((const float4*)(p.D0w + (size_t)r * H))[wg * 64 + lane];
      float4 x = ((const float4*)h1_new)[wg * 64 + lane];
      float s = a.x * x.x + a.y * x.y + a.z * x.z + a.w * x.w;
#pragma unroll
      for (int off = 32; off; off >>= 1) s += __shfl_xor(s, off, 64);
      if (lane == 0) s_red[wave] = s;
      __syncthreads();
      if (tid < 4) {
        int r2 = 4 * b + tid;
        float tot = s_red[tid * 4] + s_red[tid * 4 + 1] + s_red[tid * 4 + 2] +
                    s_red[tid * 4 + 3];
        a0[r2] = ftanh(tot + p.D0b[r2]);
      }
    }
    gbar(bar);

    // ---- Phase G: d = tanh(D1w@a0 + D1b); conv partial into dec ----
    {
      const int r = 4 * b + sg;
      float4 a = ((const float4*)(p.D1w + (size_t)r * H))[wg * 64 + lane];
      float4 x = ((const float4*)a0)[wg * 64 + lane];
      float s = a.x * x.x + a.y * x.y + a.z * x.z + a.w * x.w;
#pragma unroll
      for (int off = 32; off; off >>= 1) s += __shfl_xor(s, off, 64);
      if (lane == 0) s_red[wave] = s;
      __syncthreads();
      if (tid < 4) {
        int r2 = 4 * b + tid;
        float tot = s_red[tid * 4] + s_red[tid * 4 + 1] + s_red[tid * 4 + 2] +
                    s_red[tid * 4 + 3];
        s_d[tid] = ftanh(tot + p.D1b[r2]);
      }
      __syncthreads();
      if (tid < 2 * MEL) {
        float acc = 0.f;
#pragma unroll
        for (int w = 0; w < 4; ++w)
          acc += p.conv_w[tid * H + 4 * b + w] * s_d[w];
        atomicAdd(&dec[tid], acc);
      }
    }
    gbar(bar);
  }

  // ---- epilogue: output for t = T-1 (total[0]) ----
  if (b == 0 && tid < MEL) {
    float ls = dec[tid] + p.conv_b[tid];
    float bb = dec[MEL + tid] + p.conv_b[MEL + tid];
    float r = p.residual[tid];
    p.out[tid] = (r - bb) * __expf(-ls);
  }
}

extern "C" void kernel_launch(void* const* d_in, const int* in_sizes, int n_in,
                              void* d_out, int out_size, void* d_ws, size_t ws_size,
                              hipStream_t stream) {
  Params hp;
  hp.residual = (const float*)d_in[0];
  hp.text = (const float*)d_in[1];
  hp.Wih_a = (const float*)d_in[2];
  hp.Whh_a = (const float*)d_in[3];
  hp.bih_a = (const float*)d_in[4];
  hp.bhh_a = (const float*)d_in[5];
  hp.Wq = (const float*)d_in[6];
  hp.Wk = (const float*)d_in[7];
  hp.Wv = (const float*)d_in[8];
  hp.v_w = (const float*)d_in[9];
  hp.Wih0 = (const float*)d_in[10];
  hp.Whh0 = (const float*)d_in[11];
  hp.bih0 = (const float*)d_in[12];
  hp.bhh0 = (const float*)d_in[13];
  hp.Wih1 = (const float*)d_in[14];
  hp.Whh1 = (const float*)d_in[15];
  hp.bih1 = (const float*)d_in[16];
  hp.bhh1 = (const float*)d_in[17];
  hp.D0w = (const float*)d_in[18];
  hp.D0b = (const float*)d_in[19];
  hp.D1w = (const float*)d_in[20];
  hp.D1b = (const float*)d_in[21];
  hp.conv_w = (const float*)d_in[22];
  hp.conv_b = (const float*)d_in[23];
  hp.gate_w = (const float*)d_in[24];
  hp.gate_b = (const float*)d_in[25];
  hp.out = (float*)d_out;
  hp.ws = (float*)d_ws;

  // barrier counter must be 0 before the kernel runs (ws is poisoned 0xAA
  // before every timed launch; memset node is graph-capturable).
  hipMemsetAsync((char*)d_ws + (size_t)WS_BAR * sizeof(float), 0, 256, stream);

  void* args[] = {&hp};
  hipLaunchCooperativeKernel((void*)ar_kernel, dim3(NBLK), dim3(NTHR), args, 0,
                             stream);
}

// Round 5
// 59139.929 us; speedup vs baseline: 2.4583x; 1.5130x over previous
//
#include <hip/hip_runtime.h>

#define NBLK 256
#define NTHR 1024

constexpr int H = 1024, MEL = 80, ATT = 640, TXTD = 640, T = 600, TTXT = 128;
constexpr int G4 = 4096, DIN = H + ATT; // 1664

// ---- workspace layout (floats) ----
constexpr int WS_K     = 0;                  // 128*640
constexpr int WS_V     = WS_K + TTXT * ATT;  // 128*640
constexpr int WS_HBUF  = WS_V + TTXT * ATT;  // 2*1024 (double buffer)
constexpr int WS_C     = WS_HBUF + 2 * H;    // 1024
constexpr int WS_H0BUF = WS_C + H;           // 2*1024
constexpr int WS_C0    = WS_H0BUF + 2 * H;   // 1024
constexpr int WS_H1BUF = WS_C0 + H;          // 2*1024
constexpr int WS_C1    = WS_H1BUF + 2 * H;   // 1024
constexpr int WS_Q     = WS_C1 + H;          // 640
constexpr int WS_W0H   = WS_Q + ATT;         // 4096 (Wih0[:, :1024] @ h)
constexpr int WS_U0    = WS_W0H + G4;        // 4096 (Whh0 @ h0_prev)
constexpr int WS_U1    = WS_U0 + G4;         // 4096 (Whh1 @ h1_prev)
constexpr int WS_CTX   = WS_U1 + G4;         // 640 (unnormalized ctx accum)
constexpr int WS_DEN   = WS_CTX + ATT;       // 1  (softmax denom)
constexpr int WS_GH    = WS_DEN + 1;         // 1  (gate_w[:1024]@h)
constexpr int WS_DEC   = (WS_GH + 1 + 15) & ~15;   // 160 (conv accum), 16-aligned
constexpr int WS_A0    = (WS_DEC + 2 * MEL + 15) & ~15;  // 1024, 16-aligned
constexpr int WS_END   = WS_A0 + H;
constexpr int WS_BAR   = (WS_END + 63) & ~63;  // barrier area (u32s)
// barrier: 16 leaf counters 128B apart, root at +512 u32, epoch at +544 u32

struct Params {
  const float *residual, *text, *Wih_a, *Whh_a, *bih_a, *bhh_a,
      *Wq, *Wk, *Wv, *v_w, *Wih0, *Whh0, *bih0, *bhh0,
      *Wih1, *Whh1, *bih1, *bhh1, *D0w, *D0b, *D1w, *D1b,
      *conv_w, *conv_b, *gate_w, *gate_b;
  float* out;
  float* ws;
};

__device__ __forceinline__ float sigm(float x) { return 1.0f / (1.0f + __expf(-x)); }
__device__ __forceinline__ float ftanh(float x) {
  x = fminf(15.f, fmaxf(-15.f, x));
  float e = __expf(2.f * x);
  return (e - 1.f) / (e + 1.f);
}

// Hierarchical grid barrier: 16 padded leaf counters (parallel arrival RMWs),
// last leaf arriver bumps root, last root arriver bumps epoch; all poll epoch.
__device__ __forceinline__ void gbar(unsigned* bar, unsigned k) {
  __syncthreads();
  if (threadIdx.x == 0) {
    __threadfence();  // release
    unsigned* leaf = bar + (blockIdx.x & 15) * 32;  // 128B apart
    unsigned o = __hip_atomic_fetch_add(leaf, 1u, __ATOMIC_RELAXED,
                                        __HIP_MEMORY_SCOPE_AGENT);
    if ((o & 15) == 15) {  // 16 arrivals per leaf
      unsigned r = __hip_atomic_fetch_add(bar + 512, 1u, __ATOMIC_RELAXED,
                                          __HIP_MEMORY_SCOPE_AGENT);
      if ((r & 15) == 15)
        __hip_atomic_fetch_add(bar + 544, 1u, __ATOMIC_RELAXED,
                               __HIP_MEMORY_SCOPE_AGENT);
    }
    while (__hip_atomic_load(bar + 544, __ATOMIC_RELAXED,
                             __HIP_MEMORY_SCOPE_AGENT) < k)
      __builtin_amdgcn_s_sleep(1);
    __threadfence();  // acquire
  }
  __syncthreads();
}

__device__ __forceinline__ float red64(float s) {
#pragma unroll
  for (int off = 32; off; off >>= 1) s += __shfl_xor(s, off, 64);
  return s;
}

// partial dot of 1024-length row held in 4 pinned float4s vs x (per-lane)
__device__ __forceinline__ float dot16pin(float4 w0, float4 w1, float4 w2,
                                          float4 w3, const float* x, int lane) {
  const float4* x4 = (const float4*)x;
  float4 b0 = x4[lane], b1 = x4[lane + 64], b2 = x4[lane + 128],
         b3 = x4[lane + 192];
  float s0 = w0.x * b0.x, s1 = w1.x * b1.x;
  s0 = fmaf(w0.y, b0.y, s0); s1 = fmaf(w1.y, b1.y, s1);
  s0 = fmaf(w0.z, b0.z, s0); s1 = fmaf(w1.z, b1.z, s1);
  s0 = fmaf(w0.w, b0.w, s0); s1 = fmaf(w1.w, b1.w, s1);
  s0 = fmaf(w2.x, b2.x, s0); s1 = fmaf(w3.x, b3.x, s1);
  s0 = fmaf(w2.y, b2.y, s0); s1 = fmaf(w3.y, b3.y, s1);
  s0 = fmaf(w2.z, b2.z, s0); s1 = fmaf(w3.z, b3.z, s1);
  s0 = fmaf(w2.w, b2.w, s0); s1 = fmaf(w3.w, b3.w, s1);
  return s0 + s1;
}

// partial dot of streamed 1024-length row vs x (per-lane)
__device__ __forceinline__ float dot16load(const float* __restrict__ w,
                                           const float* __restrict__ x,
                                           int lane) {
  const float4* w4 = (const float4*)w;
  const float4* x4 = (const float4*)x;
  float4 a0 = w4[lane], a1 = w4[lane + 64], a2 = w4[lane + 128],
         a3 = w4[lane + 192];
  float4 b0 = x4[lane], b1 = x4[lane + 64], b2 = x4[lane + 128],
         b3 = x4[lane + 192];
  float s0 = a0.x * b0.x, s1 = a1.x * b1.x;
  s0 = fmaf(a0.y, b0.y, s0); s1 = fmaf(a1.y, b1.y, s1);
  s0 = fmaf(a0.z, b0.z, s0); s1 = fmaf(a1.z, b1.z, s1);
  s0 = fmaf(a0.w, b0.w, s0); s1 = fmaf(a1.w, b1.w, s1);
  s0 = fmaf(a2.x, b2.x, s0); s1 = fmaf(a3.x, b3.x, s1);
  s0 = fmaf(a2.y, b2.y, s0); s1 = fmaf(a3.y, b3.y, s1);
  s0 = fmaf(a2.z, b2.z, s0); s1 = fmaf(a3.z, b3.z, s1);
  s0 = fmaf(a2.w, b2.w, s0); s1 = fmaf(a3.w, b3.w, s1);
  return s0 + s1;
}

__device__ __forceinline__ float wave_dot(const float* __restrict__ w,
                                          const float* __restrict__ x,
                                          int n4, int lane) {
  float s = 0.f;
  const float4* w4 = (const float4*)w;
  const float4* x4 = (const float4*)x;
  for (int i = lane; i < n4; i += 64) {
    float4 a = w4[i];
    float4 b = x4[i];
    s = fmaf(a.x, b.x, s);
    s = fmaf(a.y, b.y, s);
    s = fmaf(a.z, b.z, s);
    s = fmaf(a.w, b.w, s);
  }
  return red64(s);
}

__global__ void __launch_bounds__(NTHR, 4) ar_kernel(Params p) {
  const int b = blockIdx.x;
  const int tid = threadIdx.x;
  const int wave = tid >> 6;   // 0..15
  const int lane = tid & 63;
  const int sg = wave >> 2;    // element subgroup 0..3
  const int wg = wave & 3;     // gate / k-chunk within subgroup
  const int gw = b * 16 + wave;  // global wave 0..4095

  float* ws = p.ws;
  float* Kw = ws + WS_K;
  float* Vw = ws + WS_V;
  float* hbuf = ws + WS_HBUF;
  float* carr = ws + WS_C;
  float* h0buf = ws + WS_H0BUF;
  float* c0arr = ws + WS_C0;
  float* h1buf = ws + WS_H1BUF;
  float* c1arr = ws + WS_C1;
  float* qv = ws + WS_Q;
  float* w0h = ws + WS_W0H;
  float* u0 = ws + WS_U0;
  float* u1 = ws + WS_U1;
  float* ctxa = ws + WS_CTX;
  float* den = ws + WS_DEN;
  float* ghp = ws + WS_GH;
  float* dec = ws + WS_DEC;
  float* a0 = ws + WS_A0;
  unsigned* bar = (unsigned*)(ws + WS_BAR);

  __shared__ __align__(16) float s_out[MEL];
  __shared__ __align__(16) float s_ctx[ATT];
  __shared__ float s_red[16];
  __shared__ float s_d[4];

  const int e = 4 * b + sg;
  const int grow = e + wg * H;  // row for phases A(gate), D, E

  // ---- pin invariant weight rows in registers (constant across all t) ----
  const float4* WA = (const float4*)(p.Whh_a + (size_t)grow * H);
  float4 wa0 = WA[lane], wa1 = WA[lane + 64], wa2 = WA[lane + 128],
         wa3 = WA[lane + 192];
  const float4* W0 = (const float4*)(p.Whh0 + (size_t)gw * H);
  float4 w00 = W0[lane], w01 = W0[lane + 64], w02 = W0[lane + 128],
         w03 = W0[lane + 192];
  const float4* W1 = (const float4*)(p.Whh1 + (size_t)gw * H);
  float4 w10 = W1[lane], w11 = W1[lane + 64], w12 = W1[lane + 128],
         w13 = W1[lane + 192];
  const float4* WI = (const float4*)(p.Wih1 + (size_t)grow * H);
  float4 wi0 = WI[lane], wi1 = WI[lane + 64], wi2 = WI[lane + 128],
         wi3 = WI[lane + 192];
  float4 wma = make_float4(0.f, 0.f, 0.f, 0.f);
  if (lane < MEL / 4)
    wma = ((const float4*)(p.Wih_a + (size_t)grow * MEL))[lane];
  float4 wf = ((const float4*)(p.D0w + (size_t)e * H))[wg * 64 + lane];
  float4 wgd = ((const float4*)(p.D1w + (size_t)e * H))[wg * 64 + lane];
  float4 wcv = make_float4(0.f, 0.f, 0.f, 0.f);
  if (tid < 2 * MEL) wcv = ((const float4*)(p.conv_w + (size_t)tid * H))[b];
  const float ba = p.bih_a[grow] + p.bhh_a[grow];
  const float b0s = p.bih0[grow] + p.bhh0[grow];
  const float b1s = p.bih1[grow] + p.bhh1[grow];

  unsigned bk = 0;

  // ---------------- init: zero state, precompute K,V ----------------
  if (b == 0) {
    for (int i = tid; i < 9 * H; i += NTHR) hbuf[i] = 0.f;  // h,c,h0,c0,h1,c1
  }
  for (int idx = gw; idx < 2 * TTXT * ATT; idx += NBLK * 16) {
    int isV = idx >= TTXT * ATT;
    int rem = isV ? idx - TTXT * ATT : idx;
    int j = rem / ATT;
    int a = rem - j * ATT;
    const float* wrow = (isV ? p.Wv : p.Wk) + a * TXTD;
    float s = wave_dot(wrow, p.text + j * TXTD, TXTD / 4, lane);
    if (lane == 0) (isV ? Vw : Kw)[j * ATT + a] = s;
  }
  gbar(bar, ++bk);

  // ---------------- main sequential loop ----------------
  for (int t = 0; t < T; ++t) {
    const float* h_old = hbuf + (t & 1) * H;
    float* h_new = hbuf + ((t + 1) & 1) * H;
    const float* h0_old = h0buf + (t & 1) * H;
    float* h0_new = h0buf + ((t + 1) & 1) * H;
    const float* h1_old = h1buf + (t & 1) * H;
    float* h1_new = h1buf + ((t + 1) & 1) * H;

    // ---- Phase A: prev output; attn-LSTM gate (pinned) + u0/u1 (pinned) ----
    if (tid < MEL) {
      float o;
      if (t == 0) {
        o = 0.f;
      } else {
        float ls = dec[tid] + p.conv_b[tid];
        float bb = dec[MEL + tid] + p.conv_b[MEL + tid];
        float r = p.residual[(T - t) * MEL + tid];
        o = (r - bb) * __expf(-ls);
        if (b == 0) p.out[(T - t) * MEL + tid] = o;
      }
      s_out[tid] = o;
    }
    __syncthreads();

    {
      float pa = dot16pin(wa0, wa1, wa2, wa3, h_old, lane);
      if (lane < MEL / 4) {
        float4 bm = ((const float4*)s_out)[lane];
        pa = fmaf(wma.x, bm.x, pa);
        pa = fmaf(wma.y, bm.y, pa);
        pa = fmaf(wma.z, bm.z, pa);
        pa = fmaf(wma.w, bm.w, pa);
      }
      float pu0 = dot16pin(w00, w01, w02, w03, h0_old, lane);
      float pu1 = dot16pin(w10, w11, w12, w13, h1_old, lane);
      pa = red64(pa);
      pu0 = red64(pu0);
      pu1 = red64(pu1);
      if (lane == 0) {
        u0[gw] = pu0;
        u1[gw] = pu1;
        s_red[wave] = pa + ba;
      }
      __syncthreads();
      if (tid < 4) {
        int ee = 4 * b + tid;
        float gi = s_red[tid * 4 + 0], gf = s_red[tid * 4 + 1];
        float gg = s_red[tid * 4 + 2], go = s_red[tid * 4 + 3];
        float c2 = sigm(gf) * carr[ee] + sigm(gi) * ftanh(gg);
        carr[ee] = c2;
        h_new[ee] = sigm(go) * ftanh(c2);
      }
    }
    gbar(bar, ++bk);

    // ---- Phase B: w0h row per wave (streamed); Wq/gate rows; zero scratch ----
    {
      float s0 = dot16load(p.Wih0 + (size_t)gw * DIN, h_new, lane);
      s0 = red64(s0);
      if (lane == 0) w0h[gw] = s0;
      if (gw < ATT) {
        float q = dot16load(p.Wq + (size_t)gw * H, h_new, lane);
        q = red64(q);
        if (lane == 0) qv[gw] = q;
      } else if (gw == ATT) {
        float q = dot16load(p.gate_w, h_new, lane);
        q = red64(q);
        if (lane == 0) ghp[0] = q;
      }
      if (b == NBLK - 1) {
        for (int i = tid; i < ATT; i += NTHR) ctxa[i] = 0.f;
        if (tid == 0) den[0] = 0.f;
        for (int i = tid; i < 2 * MEL; i += NTHR) dec[i] = 0.f;
      }
    }
    gbar(bar, ++bk);

    // ---- Phase C: scores -> exp -> ctx accumulation (fixed-shift softmax) ----
    if (b < TTXT) {
      const int j = b;
      float sp = 0.f;
      for (int i = tid; i < ATT; i += NTHR)
        sp += ftanh(qv[i] + Kw[j * ATT + i]) * p.v_w[i];
      sp = red64(sp);
      if (lane == 0) s_red[wave] = sp;
      __syncthreads();
      float sc = 0.f;
#pragma unroll
      for (int k = 0; k < 16; ++k) sc += s_red[k];
      float pj = __expf(sc - 16.f);  // scores bounded ~±11, shift is safe
      for (int i = tid; i < ATT; i += NTHR)
        atomicAdd(&ctxa[i], pj * Vw[j * ATT + i]);
      if (tid == 0) atomicAdd(den, pj);
    }
    gbar(bar, ++bk);

    // ---- Phase D: dec LSTM0: ctx-part row per wave (streamed 640) ----
    {
      float inv = 1.f / den[0];
      for (int i = tid; i < ATT; i += NTHR) s_ctx[i] = ctxa[i] * inv;
      __syncthreads();
      const float4* W4 = (const float4*)(p.Wih0 + (size_t)grow * DIN + H);
      const float4* X4 = (const float4*)s_ctx;
      float4 a_ = W4[lane], b_ = X4[lane];
      float4 a2 = W4[lane + 64], b2 = X4[lane + 64];
      float s = a_.x * b_.x;
      s = fmaf(a_.y, b_.y, s); s = fmaf(a_.z, b_.z, s); s = fmaf(a_.w, b_.w, s);
      s = fmaf(a2.x, b2.x, s); s = fmaf(a2.y, b2.y, s);
      s = fmaf(a2.z, b2.z, s); s = fmaf(a2.w, b2.w, s);
      if (lane < 32) {
        float4 a3 = W4[128 + lane], b3 = X4[128 + lane];
        s = fmaf(a3.x, b3.x, s); s = fmaf(a3.y, b3.y, s);
        s = fmaf(a3.z, b3.z, s); s = fmaf(a3.w, b3.w, s);
      }
      s = red64(s);
      if (lane == 0)
        s_red[wave] = s + w0h[grow] + u0[grow] + b0s;
      if (b == 0 && wave == 15) {
        float gc = wave_dot(p.gate_w + H, s_ctx, ATT / 4, lane);
        if (lane == 0) p.out[T * MEL + t] = sigm(ghp[0] + gc + p.gate_b[0]);
      }
      __syncthreads();
      if (tid < 4) {
        int ee = 4 * b + tid;
        float gi = s_red[tid * 4 + 0], gf = s_red[tid * 4 + 1];
        float gg = s_red[tid * 4 + 2], go = s_red[tid * 4 + 3];
        float c2 = sigm(gf) * c0arr[ee] + sigm(gi) * ftanh(gg);
        c0arr[ee] = c2;
        h0_new[ee] = sigm(go) * ftanh(c2);
      }
    }
    gbar(bar, ++bk);

    // ---- Phase E: dec LSTM1 (pinned Wih1 row) ----
    {
      float pe = dot16pin(wi0, wi1, wi2, wi3, h0_new, lane);
      pe = red64(pe);
      if (lane == 0) s_red[wave] = pe + u1[grow] + b1s;
      __syncthreads();
      if (tid < 4) {
        int ee = 4 * b + tid;
        float gi = s_red[tid * 4 + 0], gf = s_red[tid * 4 + 1];
        float gg = s_red[tid * 4 + 2], go = s_red[tid * 4 + 3];
        float c2 = sigm(gf) * c1arr[ee] + sigm(gi) * ftanh(gg);
        c1arr[ee] = c2;
        h1_new[ee] = sigm(go) * ftanh(c2);
      }
    }
    gbar(bar, ++bk);

    // ---- Phase F: a0 = tanh(D0w@h1 + D0b); pinned D0w f4, k-split 4 waves ----
    {
      float4 x = ((const float4*)h1_new)[wg * 64 + lane];
      float s = wf.x * x.x;
      s = fmaf(wf.y, x.y, s); s = fmaf(wf.z, x.z, s); s = fmaf(wf.w, x.w, s);
      s = red64(s);
      if (lane == 0) s_red[wave] = s;
      __syncthreads();
      if (tid < 4) {
        int r2 = 4 * b + tid;
        float tot = s_red[tid * 4] + s_red[tid * 4 + 1] + s_red[tid * 4 + 2] +
                    s_red[tid * 4 + 3];
        a0[r2] = ftanh(tot + p.D0b[r2]);
      }
    }
    gbar(bar, ++bk);

    // ---- Phase G: d = tanh(D1w@a0 + D1b); conv partial into dec ----
    {
      float4 x = ((const float4*)a0)[wg * 64 + lane];
      float s = wgd.x * x.x;
      s = fmaf(wgd.y, x.y, s); s = fmaf(wgd.z, x.z, s); s = fmaf(wgd.w, x.w, s);
      s = red64(s);
      if (lane == 0) s_red[wave] = s;
      __syncthreads();
      if (tid < 4) {
        int r2 = 4 * b + tid;
        float tot = s_red[tid * 4] + s_red[tid * 4 + 1] + s_red[tid * 4 + 2] +
                    s_red[tid * 4 + 3];
        s_d[tid] = ftanh(tot + p.D1b[r2]);
      }
      __syncthreads();
      if (tid < 2 * MEL) {
        float acc = wcv.x * s_d[0];
        acc = fmaf(wcv.y, s_d[1], acc);
        acc = fmaf(wcv.z, s_d[2], acc);
        acc = fmaf(wcv.w, s_d[3], acc);
        atomicAdd(&dec[tid], acc);
      }
    }
    gbar(bar, ++bk);
  }

  // ---- epilogue: output for t = T-1 (total[0]) ----
  if (b == 0 && tid < MEL) {
    float ls = dec[tid] + p.conv_b[tid];
    float bb = dec[MEL + tid] + p.conv_b[MEL + tid];
    float r = p.residual[tid];
    p.out[tid] = (r - bb) * __expf(-ls);
  }
}

extern "C" void kernel_launch(void* const* d_in, const int* in_sizes, int n_in,
                              void* d_out, int out_size, void* d_ws, size_t ws_size,
                              hipStream_t stream) {
  Params hp;
  hp.residual = (const float*)d_in[0];
  hp.text = (const float*)d_in[1];
  hp.Wih_a = (const float*)d_in[2];
  hp.Whh_a = (const float*)d_in[3];
  hp.bih_a = (const float*)d_in[4];
  hp.bhh_a = (const float*)d_in[5];
  hp.Wq = (const float*)d_in[6];
  hp.Wk = (const float*)d_in[7];
  hp.Wv = (const float*)d_in[8];
  hp.v_w = (const float*)d_in[9];
  hp.Wih0 = (const float*)d_in[10];
  hp.Whh0 = (const float*)d_in[11];
  hp.bih0 = (const float*)d_in[12];
  hp.bhh0 = (const float*)d_in[13];
  hp.Wih1 = (const float*)d_in[14];
  hp.Whh1 = (const float*)d_in[15];
  hp.bih1 = (const float*)d_in[16];
  hp.bhh1 = (const float*)d_in[17];
  hp.D0w = (const float*)d_in[18];
  hp.D0b = (const float*)d_in[19];
  hp.D1w = (const float*)d_in[20];
  hp.D1b = (const float*)d_in[21];
  hp.conv_w = (const float*)d_in[22];
  hp.conv_b = (const float*)d_in[23];
  hp.gate_w = (const float*)d_in[24];
  hp.gate_b = (const float*)d_in[25];
  hp.out = (float*)d_out;
  hp.ws = (float*)d_ws;

  // barrier counters must be 0 before the kernel runs (ws is poisoned 0xAA
  // before every timed launch; memset node is graph-capturable).
  hipMemsetAsync((char*)d_ws + (size_t)WS_BAR * sizeof(float), 0, 4096, stream);

  void* args[] = {&hp};
  hipLaunchCooperativeKernel((void*)ar_kernel, dim3(NBLK), dim3(NTHR), args, 0,
                             stream);
}

// Round 6
// 27595.123 us; speedup vs baseline: 5.2685x; 2.1431x over previous
//
#include <hip/hip_runtime.h>

#define NBLK 256
#define NTHR 1024

constexpr int H = 1024, MEL = 80, ATT = 640, TXTD = 640, T = 600, TTXT = 128;
constexpr int G4 = 4096, DIN = H + ATT; // 1664

// ---- workspace layout (floats) ----
constexpr int WS_K     = 0;                  // 128*640
constexpr int WS_V     = WS_K + TTXT * ATT;  // 128*640
constexpr int WS_HBUF  = WS_V + TTXT * ATT;  // 2*1024 (double buffer)
constexpr int WS_H0BUF = WS_HBUF + 2 * H;    // 2*1024
constexpr int WS_H1BUF = WS_H0BUF + 2 * H;   // 2*1024
constexpr int WS_Q     = WS_H1BUF + 2 * H;   // 640
constexpr int WS_W0H   = WS_Q + ATT;         // 4096
constexpr int WS_U0    = WS_W0H + G4;        // 4096
constexpr int WS_U1    = WS_U0 + G4;         // 4096
constexpr int WS_CTX   = WS_U1 + G4;         // 640 (unnormalized ctx accum)
constexpr int WS_DEN   = WS_CTX + ATT;       // 1
constexpr int WS_GH    = WS_DEN + 1;         // 1
constexpr int WS_DEC   = (WS_GH + 1 + 15) & ~15;        // 160 (conv accum)
constexpr int WS_A0    = (WS_DEC + 2 * MEL + 15) & ~15; // 1024
constexpr int WS_END   = WS_A0 + H;
constexpr int WS_BAR   = (WS_END + 63) & ~63;  // barrier area (u32s)
// barrier: 16 leaf counters 128B apart, root at +512 u32, epoch at +544 u32

struct Params {
  const float *residual, *text, *Wih_a, *Whh_a, *bih_a, *bhh_a,
      *Wq, *Wk, *Wv, *v_w, *Wih0, *Whh0, *bih0, *bhh0,
      *Wih1, *Whh1, *bih1, *bhh1, *D0w, *D0b, *D1w, *D1b,
      *conv_w, *conv_b, *gate_w, *gate_b;
  float* out;
  float* ws;
};

__device__ __forceinline__ float sigm(float x) { return 1.0f / (1.0f + __expf(-x)); }
__device__ __forceinline__ float ftanh(float x) {
  x = fminf(15.f, fmaxf(-15.f, x));
  float e = __expf(2.f * x);
  return (e - 1.f) / (e + 1.f);
}

// Coherent (agent-scope, cache-bypassing) accessors for mutable ws data.
__device__ __forceinline__ float aload(const float* p) {
  return __hip_atomic_load(p, __ATOMIC_RELAXED, __HIP_MEMORY_SCOPE_AGENT);
}
__device__ __forceinline__ void astore(float* p, float v) {
  __hip_atomic_store(p, v, __ATOMIC_RELAXED, __HIP_MEMORY_SCOPE_AGENT);
}

// Fence-light grid barrier: no __threadfence (no L2 wb/inv!). Each thread
// drains its own vmem (s_waitcnt vmcnt(0)); data is transferred exclusively
// through agent-scope atomics which are coherent at the MALL, so once the
// stores have retired they are globally visible. Then a hierarchical
// relaxed-atomic arrival tree: 16 padded leaves -> root -> epoch.
__device__ __forceinline__ void gbar(unsigned* bar, unsigned k) {
  asm volatile("s_waitcnt vmcnt(0)" ::: "memory");
  __syncthreads();
  if (threadIdx.x == 0) {
    unsigned* leaf = bar + (blockIdx.x & 15) * 32;  // 128B apart
    unsigned o = __hip_atomic_fetch_add(leaf, 1u, __ATOMIC_RELAXED,
                                        __HIP_MEMORY_SCOPE_AGENT);
    if ((o & 15) == 15) {  // 16 arrivals per leaf
      unsigned r = __hip_atomic_fetch_add(bar + 512, 1u, __ATOMIC_RELAXED,
                                          __HIP_MEMORY_SCOPE_AGENT);
      if ((r & 15) == 15)
        __hip_atomic_fetch_add(bar + 544, 1u, __ATOMIC_RELAXED,
                               __HIP_MEMORY_SCOPE_AGENT);
    }
    while (__hip_atomic_load(bar + 544, __ATOMIC_RELAXED,
                             __HIP_MEMORY_SCOPE_AGENT) < k)
      __builtin_amdgcn_s_sleep(1);
  }
  __syncthreads();
}

__device__ __forceinline__ float red64(float s) {
#pragma unroll
  for (int off = 32; off; off >>= 1) s += __shfl_xor(s, off, 64);
  return s;
}

// partial dot of 1024-length row held in 4 pinned float4s vs x in LDS
__device__ __forceinline__ float dot16pin(float4 w0, float4 w1, float4 w2,
                                          float4 w3, const float* x, int lane) {
  const float4* x4 = (const float4*)x;
  float4 b0 = x4[lane], b1 = x4[lane + 64], b2 = x4[lane + 128],
         b3 = x4[lane + 192];
  float s0 = w0.x * b0.x, s1 = w1.x * b1.x;
  s0 = fmaf(w0.y, b0.y, s0); s1 = fmaf(w1.y, b1.y, s1);
  s0 = fmaf(w0.z, b0.z, s0); s1 = fmaf(w1.z, b1.z, s1);
  s0 = fmaf(w0.w, b0.w, s0); s1 = fmaf(w1.w, b1.w, s1);
  s0 = fmaf(w2.x, b2.x, s0); s1 = fmaf(w3.x, b3.x, s1);
  s0 = fmaf(w2.y, b2.y, s0); s1 = fmaf(w3.y, b3.y, s1);
  s0 = fmaf(w2.z, b2.z, s0); s1 = fmaf(w3.z, b3.z, s1);
  s0 = fmaf(w2.w, b2.w, s0); s1 = fmaf(w3.w, b3.w, s1);
  return s0 + s1;
}

// partial dot of streamed (cached) 1024-length row vs x in LDS
__device__ __forceinline__ float dot16load(const float* __restrict__ w,
                                           const float* __restrict__ x,
                                           int lane) {
  const float4* w4 = (const float4*)w;
  const float4* x4 = (const float4*)x;
  float4 a0 = w4[lane], a1 = w4[lane + 64], a2 = w4[lane + 128],
         a3 = w4[lane + 192];
  float4 b0 = x4[lane], b1 = x4[lane + 64], b2 = x4[lane + 128],
         b3 = x4[lane + 192];
  float s0 = a0.x * b0.x, s1 = a1.x * b1.x;
  s0 = fmaf(a0.y, b0.y, s0); s1 = fmaf(a1.y, b1.y, s1);
  s0 = fmaf(a0.z, b0.z, s0); s1 = fmaf(a1.z, b1.z, s1);
  s0 = fmaf(a0.w, b0.w, s0); s1 = fmaf(a1.w, b1.w, s1);
  s0 = fmaf(a2.x, b2.x, s0); s1 = fmaf(a3.x, b3.x, s1);
  s0 = fmaf(a2.y, b2.y, s0); s1 = fmaf(a3.y, b3.y, s1);
  s0 = fmaf(a2.z, b2.z, s0); s1 = fmaf(a3.z, b3.z, s1);
  s0 = fmaf(a2.w, b2.w, s0); s1 = fmaf(a3.w, b3.w, s1);
  return s0 + s1;
}

__device__ __forceinline__ float wave_dot(const float* __restrict__ w,
                                          const float* __restrict__ x,
                                          int n4, int lane) {
  float s = 0.f;
  const float4* w4 = (const float4*)w;
  const float4* x4 = (const float4*)x;
  for (int i = lane; i < n4; i += 64) {
    float4 a = w4[i];
    float4 b = x4[i];
    s = fmaf(a.x, b.x, s);
    s = fmaf(a.y, b.y, s);
    s = fmaf(a.z, b.z, s);
    s = fmaf(a.w, b.w, s);
  }
  return red64(s);
}

__global__ void __launch_bounds__(NTHR, 4) ar_kernel(Params p) {
  const int b = blockIdx.x;
  const int tid = threadIdx.x;
  const int wave = tid >> 6;   // 0..15
  const int lane = tid & 63;
  const int sg = wave >> 2;    // element subgroup 0..3
  const int wg = wave & 3;     // gate / k-chunk within subgroup
  const int gw = b * 16 + wave;  // global wave 0..4095

  float* ws = p.ws;
  float* Kw = ws + WS_K;
  float* Vw = ws + WS_V;
  float* hbuf = ws + WS_HBUF;
  float* h0buf = ws + WS_H0BUF;
  float* h1buf = ws + WS_H1BUF;
  float* qv = ws + WS_Q;
  float* w0h = ws + WS_W0H;
  float* u0 = ws + WS_U0;
  float* u1 = ws + WS_U1;
  float* ctxa = ws + WS_CTX;
  float* den = ws + WS_DEN;
  float* ghp = ws + WS_GH;
  float* dec = ws + WS_DEC;
  float* a0 = ws + WS_A0;
  unsigned* bar = (unsigned*)(ws + WS_BAR);

  __shared__ __align__(16) float s_h[H];
  __shared__ __align__(16) float s_h0[H];
  __shared__ __align__(16) float s_h1[H];
  __shared__ __align__(16) float s_att[ATT];
  __shared__ __align__(16) float s_out[MEL];
  __shared__ float s_dec[2 * MEL];
  __shared__ float s_red[16];
  __shared__ float s_d[4];
  __shared__ float s_den_sh;

  const int e = 4 * b + sg;
  const int grow = e + wg * H;  // row for phases A(gate), D, E

  // ---- pin invariant weight rows in registers (constant across all t) ----
  const float4* WA = (const float4*)(p.Whh_a + (size_t)grow * H);
  float4 wa0 = WA[lane], wa1 = WA[lane + 64], wa2 = WA[lane + 128],
         wa3 = WA[lane + 192];
  const float4* W0 = (const float4*)(p.Whh0 + (size_t)gw * H);
  float4 w00 = W0[lane], w01 = W0[lane + 64], w02 = W0[lane + 128],
         w03 = W0[lane + 192];
  const float4* W1 = (const float4*)(p.Whh1 + (size_t)gw * H);
  float4 w10 = W1[lane], w11 = W1[lane + 64], w12 = W1[lane + 128],
         w13 = W1[lane + 192];
  const float4* WI = (const float4*)(p.Wih1 + (size_t)grow * H);
  float4 wi0 = WI[lane], wi1 = WI[lane + 64], wi2 = WI[lane + 128],
         wi3 = WI[lane + 192];
  float4 wma = make_float4(0.f, 0.f, 0.f, 0.f);
  if (lane < MEL / 4)
    wma = ((const float4*)(p.Wih_a + (size_t)grow * MEL))[lane];
  float4 wf = ((const float4*)(p.D0w + (size_t)e * H))[wg * 64 + lane];
  float4 wgd = ((const float4*)(p.D1w + (size_t)e * H))[wg * 64 + lane];
  float4 wcv = make_float4(0.f, 0.f, 0.f, 0.f);
  if (tid < 2 * MEL) wcv = ((const float4*)(p.conv_w + (size_t)tid * H))[b];
  const float ba = p.bih_a[grow] + p.bhh_a[grow];
  const float b0s = p.bih0[grow] + p.bhh0[grow];
  const float b1s = p.bih1[grow] + p.bhh1[grow];

  // block-private LSTM cell states (element 4b+tid, threads 0..3 only)
  float c_reg = 0.f, c0_reg = 0.f, c1_reg = 0.f;

  unsigned bk = 0;

  // ---------------- init: zero state, precompute K,V (atomic stores) -------
  if (b == 0) {
    for (int i = tid; i < 6 * H; i += NTHR) astore(&hbuf[i], 0.f);
  }
  for (int idx = gw; idx < 2 * TTXT * ATT; idx += NBLK * 16) {
    int isV = idx >= TTXT * ATT;
    int rem = isV ? idx - TTXT * ATT : idx;
    int j = rem / ATT;
    int a = rem - j * ATT;
    const float* wrow = (isV ? p.Wv : p.Wk) + a * TXTD;
    float s = wave_dot(wrow, p.text + j * TXTD, TXTD / 4, lane);
    if (lane == 0) astore(&(isV ? Vw : Kw)[j * ATT + a], s);
  }
  gbar(bar, ++bk);

  // ---------------- main sequential loop ----------------
  for (int t = 0; t < T; ++t) {
    const float* h_old = hbuf + (t & 1) * H;
    float* h_new = hbuf + ((t + 1) & 1) * H;
    const float* h0_old = h0buf + (t & 1) * H;
    float* h0_new = h0buf + ((t + 1) & 1) * H;
    const float* h1_old = h1buf + (t & 1) * H;
    float* h1_new = h1buf + ((t + 1) & 1) * H;

    // ---- Phase A: stage prev state; prev output; gates + u0/u1 (pinned) ----
    s_h[tid] = aload(h_old + tid);
    s_h0[tid] = aload(h0_old + tid);
    s_h1[tid] = aload(h1_old + tid);
    if (tid < 2 * MEL) s_dec[tid] = aload(dec + tid);
    __syncthreads();
    if (tid < MEL) {
      float o = 0.f;
      if (t != 0) {
        float ls = s_dec[tid] + p.conv_b[tid];
        float bb = s_dec[MEL + tid] + p.conv_b[MEL + tid];
        float r = p.residual[(T - t) * MEL + tid];
        o = (r - bb) * __expf(-ls);
        if (b == 0) p.out[(T - t) * MEL + tid] = o;
      }
      s_out[tid] = o;
    }
    __syncthreads();
    {
      float pa = dot16pin(wa0, wa1, wa2, wa3, s_h, lane);
      if (lane < MEL / 4) {
        float4 bm = ((const float4*)s_out)[lane];
        pa = fmaf(wma.x, bm.x, pa);
        pa = fmaf(wma.y, bm.y, pa);
        pa = fmaf(wma.z, bm.z, pa);
        pa = fmaf(wma.w, bm.w, pa);
      }
      float pu0 = dot16pin(w00, w01, w02, w03, s_h0, lane);
      float pu1 = dot16pin(w10, w11, w12, w13, s_h1, lane);
      pa = red64(pa);
      pu0 = red64(pu0);
      pu1 = red64(pu1);
      if (lane == 0) {
        astore(&u0[gw], pu0);
        astore(&u1[gw], pu1);
        s_red[wave] = pa + ba;
      }
      __syncthreads();
      if (tid < 4) {
        int ee = 4 * b + tid;
        float gi = s_red[tid * 4 + 0], gf = s_red[tid * 4 + 1];
        float gg = s_red[tid * 4 + 2], go = s_red[tid * 4 + 3];
        float c2 = sigm(gf) * c_reg + sigm(gi) * ftanh(gg);
        c_reg = c2;
        astore(&h_new[ee], sigm(go) * ftanh(c2));
      }
    }
    gbar(bar, ++bk);

    // ---- Phase B: stage h_new; w0h/Wq/gate rows (L2-cached); zero scratch --
    s_h[tid] = aload(h_new + tid);
    __syncthreads();
    {
      float s0 = dot16load(p.Wih0 + (size_t)gw * DIN, s_h, lane);
      s0 = red64(s0);
      if (lane == 0) astore(&w0h[gw], s0);
      if (gw < ATT) {
        float q = dot16load(p.Wq + (size_t)gw * H, s_h, lane);
        q = red64(q);
        if (lane == 0) astore(&qv[gw], q);
      } else if (gw == ATT) {
        float q = dot16load(p.gate_w, s_h, lane);
        q = red64(q);
        if (lane == 0) astore(&ghp[0], q);
      }
      if (b == NBLK - 1) {
        for (int i = tid; i < ATT; i += NTHR) astore(&ctxa[i], 0.f);
        if (tid == 0) astore(den, 0.f);
        for (int i = tid; i < 2 * MEL; i += NTHR) astore(&dec[i], 0.f);
      }
    }
    gbar(bar, ++bk);

    // ---- Phase C: scores -> exp -> ctx accumulation (fixed-shift softmax) --
    if (b < TTXT) {
      if (tid < ATT) s_att[tid] = aload(&qv[tid]);
      __syncthreads();
      const int j = b;
      float sp = 0.f;
      for (int i = tid; i < ATT; i += NTHR)
        sp += ftanh(s_att[i] + Kw[j * ATT + i]) * p.v_w[i];
      sp = red64(sp);
      if (lane == 0) s_red[wave] = sp;
      __syncthreads();
      float sc = 0.f;
#pragma unroll
      for (int k = 0; k < 16; ++k) sc += s_red[k];
      float pj = __expf(sc - 16.f);  // scores bounded ~±11, shift is safe
      for (int i = tid; i < ATT; i += NTHR)
        atomicAdd(&ctxa[i], pj * Vw[j * ATT + i]);
      if (tid == 0) atomicAdd(den, pj);
    }
    gbar(bar, ++bk);

    // ---- Phase D: dec LSTM0: ctx-part row per wave (unnormalized, *inv) ----
    {
      if (tid < ATT) s_att[tid] = aload(&ctxa[tid]);
      if (tid == NTHR - 1) s_den_sh = aload(den);
      __syncthreads();
      float wv = 0.f, uu = 0.f;
      if (lane == 0) {
        wv = aload(&w0h[grow]);
        uu = aload(&u0[grow]);
      }
      const float4* W4 = (const float4*)(p.Wih0 + (size_t)grow * DIN + H);
      const float4* X4 = (const float4*)s_att;
      float4 a_ = W4[lane], b_ = X4[lane];
      float4 a2 = W4[lane + 64], b2 = X4[lane + 64];
      float s = a_.x * b_.x;
      s = fmaf(a_.y, b_.y, s); s = fmaf(a_.z, b_.z, s); s = fmaf(a_.w, b_.w, s);
      s = fmaf(a2.x, b2.x, s); s = fmaf(a2.y, b2.y, s);
      s = fmaf(a2.z, b2.z, s); s = fmaf(a2.w, b2.w, s);
      if (lane < 32) {
        float4 a3 = W4[128 + lane], b3 = X4[128 + lane];
        s = fmaf(a3.x, b3.x, s); s = fmaf(a3.y, b3.y, s);
        s = fmaf(a3.z, b3.z, s); s = fmaf(a3.w, b3.w, s);
      }
      s = red64(s);
      float inv = 1.f / s_den_sh;
      if (lane == 0) s_red[wave] = s * inv + wv + uu + b0s;
      if (b == 0 && wave == 15) {
        float gc = wave_dot(p.gate_w + H, s_att, ATT / 4, lane);
        if (lane == 0) {
          float gh = aload(&ghp[0]);
          p.out[T * MEL + t] = sigm(gh + gc * inv + p.gate_b[0]);
        }
      }
      __syncthreads();
      if (tid < 4) {
        int ee = 4 * b + tid;
        float gi = s_red[tid * 4 + 0], gf = s_red[tid * 4 + 1];
        float gg = s_red[tid * 4 + 2], go = s_red[tid * 4 + 3];
        float c2 = sigm(gf) * c0_reg + sigm(gi) * ftanh(gg);
        c0_reg = c2;
        astore(&h0_new[ee], sigm(go) * ftanh(c2));
      }
    }
    gbar(bar, ++bk);

    // ---- Phase E: dec LSTM1 (pinned Wih1 row) ----
    s_h[tid] = aload(h0_new + tid);
    __syncthreads();
    {
      float u1v = 0.f;
      if (lane == 0) u1v = aload(&u1[grow]);
      float pe = dot16pin(wi0, wi1, wi2, wi3, s_h, lane);
      pe = red64(pe);
      if (lane == 0) s_red[wave] = pe + u1v + b1s;
      __syncthreads();
      if (tid < 4) {
        int ee = 4 * b + tid;
        float gi = s_red[tid * 4 + 0], gf = s_red[tid * 4 + 1];
        float gg = s_red[tid * 4 + 2], go = s_red[tid * 4 + 3];
        float c2 = sigm(gf) * c1_reg + sigm(gi) * ftanh(gg);
        c1_reg = c2;
        astore(&h1_new[ee], sigm(go) * ftanh(c2));
      }
    }
    gbar(bar, ++bk);

    // ---- Phase F: a0 = tanh(D0w@h1 + D0b); pinned D0w f4, k-split 4 waves --
    s_h[tid] = aload(h1_new + tid);
    __syncthreads();
    {
      float4 x = ((const float4*)s_h)[wg * 64 + lane];
      float s = wf.x * x.x;
      s = fmaf(wf.y, x.y, s); s = fmaf(wf.z, x.z, s); s = fmaf(wf.w, x.w, s);
      s = red64(s);
      if (lane == 0) s_red[wave] = s;
      __syncthreads();
      if (tid < 4) {
        int r2 = 4 * b + tid;
        float tot = s_red[tid * 4] + s_red[tid * 4 + 1] + s_red[tid * 4 + 2] +
                    s_red[tid * 4 + 3];
        astore(&a0[r2], ftanh(tot + p.D0b[r2]));
      }
    }
    gbar(bar, ++bk);

    // ---- Phase G: d = tanh(D1w@a0 + D1b); conv partial into dec ----
    s_h[tid] = aload(a0 + tid);
    __syncthreads();
    {
      float4 x = ((const float4*)s_h)[wg * 64 + lane];
      float s = wgd.x * x.x;
      s = fmaf(wgd.y, x.y, s); s = fmaf(wgd.z, x.z, s); s = fmaf(wgd.w, x.w, s);
      s = red64(s);
      if (lane == 0) s_red[wave] = s;
      __syncthreads();
      if (tid < 4) {
        int r2 = 4 * b + tid;
        float tot = s_red[tid * 4] + s_red[tid * 4 + 1] + s_red[tid * 4 + 2] +
                    s_red[tid * 4 + 3];
        s_d[tid] = ftanh(tot + p.D1b[r2]);
      }
      __syncthreads();
      if (tid < 2 * MEL) {
        float acc = wcv.x * s_d[0];
        acc = fmaf(wcv.y, s_d[1], acc);
        acc = fmaf(wcv.z, s_d[2], acc);
        acc = fmaf(wcv.w, s_d[3], acc);
        atomicAdd(&dec[tid], acc);
      }
    }
    gbar(bar, ++bk);
  }

  // ---- epilogue: output for t = T-1 (total[0]) ----
  if (b == 0 && tid < MEL) {
    float ls = aload(&dec[tid]) + p.conv_b[tid];
    float bb = aload(&dec[MEL + tid]) + p.conv_b[MEL + tid];
    float r = p.residual[tid];
    p.out[tid] = (r - bb) * __expf(-ls);
  }
}

extern "C" void kernel_launch(void* const* d_in, const int* in_sizes, int n_in,
                              void* d_out, int out_size, void* d_ws, size_t ws_size,
                              hipStream_t stream) {
  Params hp;
  hp.residual = (const float*)d_in[0];
  hp.text = (const float*)d_in[1];
  hp.Wih_a = (const float*)d_in[2];
  hp.Whh_a = (const float*)d_in[3];
  hp.bih_a = (const float*)d_in[4];
  hp.bhh_a = (const float*)d_in[5];
  hp.Wq = (const float*)d_in[6];
  hp.Wk = (const float*)d_in[7];
  hp.Wv = (const float*)d_in[8];
  hp.v_w = (const float*)d_in[9];
  hp.Wih0 = (const float*)d_in[10];
  hp.Whh0 = (const float*)d_in[11];
  hp.bih0 = (const float*)d_in[12];
  hp.bhh0 = (const float*)d_in[13];
  hp.Wih1 = (const float*)d_in[14];
  hp.Whh1 = (const float*)d_in[15];
  hp.bih1 = (const float*)d_in[16];
  hp.bhh1 = (const float*)d_in[17];
  hp.D0w = (const float*)d_in[18];
  hp.D0b = (const float*)d_in[19];
  hp.D1w = (const float*)d_in[20];
  hp.D1b = (const float*)d_in[21];
  hp.conv_w = (const float*)d_in[22];
  hp.conv_b = (const float*)d_in[23];
  hp.gate_w = (const float*)d_in[24];
  hp.gate_b = (const float*)d_in[25];
  hp.out = (float*)d_out;
  hp.ws = (float*)d_ws;

  // barrier counters must be 0 before the kernel runs (ws is poisoned 0xAA
  // before every timed launch; memset node is graph-capturable).
  hipMemsetAsync((char*)d_ws + (size_t)WS_BAR * sizeof(float), 0, 4096, stream);

  void* args[] = {&hp};
  hipLaunchCooperativeKernel((void*)ar_kernel, dim3(NBLK), dim3(NTHR), args, 0,
                             stream);
}

// Round 7
// 26278.070 us; speedup vs baseline: 5.5325x; 1.0501x over previous
//
#include <hip/hip_runtime.h>

#define NBLK 256
#define NTHR 1024

constexpr int H = 1024, MEL = 80, ATT = 640, TXTD = 640, T = 600, TTXT = 128;
constexpr int G4 = 4096, DIN = H + ATT; // 1664

// ---- workspace layout (floats) ----
constexpr int WS_K     = 0;                  // 128*640
constexpr int WS_V     = WS_K + TTXT * ATT;  // 128*640
constexpr int WS_HBUF  = WS_V + TTXT * ATT;  // 2*1024 (double buffer)
constexpr int WS_H0BUF = WS_HBUF + 2 * H;    // 2*1024
constexpr int WS_H1BUF = WS_H0BUF + 2 * H;   // 2*1024
constexpr int WS_Q     = WS_H1BUF + 2 * H;   // 640
constexpr int WS_CTX   = WS_Q + ATT;         // 640 (unnormalized ctx accum)
constexpr int WS_DEN   = WS_CTX + ATT;       // 1
constexpr int WS_GH    = WS_DEN + 1;         // 1
constexpr int WS_DEC   = (WS_GH + 1 + 15) & ~15;        // 160 (conv accum)
constexpr int WS_A0    = (WS_DEC + 2 * MEL + 15) & ~15; // 1024
constexpr int WS_END   = WS_A0 + H;
constexpr int WS_BAR   = (WS_END + 63) & ~63;  // barrier area (u32s)
// barrier: 16 leaf counters 128B apart, root at +512 u32, epoch at +544 u32

// ---- dynamic LDS layout (floats) ----
constexpr int SM_W0  = 0;                    // 16*1664 Wih0 rows (grow-mapped)
constexpr int SM_H   = SM_W0 + 16 * DIN;     // 1024
constexpr int SM_H0  = SM_H + H;             // 1024
constexpr int SM_H1  = SM_H0 + H;            // 1024
constexpr int SM_ATT = SM_H1 + H;            // 640
constexpr int SM_K   = SM_ATT + ATT;         // 640 (this block's K row)
constexpr int SM_V   = SM_K + ATT;           // 640
constexpr int SM_VW  = SM_V + ATT;           // 640 (v_w)
constexpr int SM_OUT = SM_VW + ATT;          // 80
constexpr int SM_DEC = SM_OUT + MEL;         // 160
constexpr int SM_RED = SM_DEC + 2 * MEL;     // 16
constexpr int SM_D   = SM_RED + 16;          // 4
constexpr int SM_DEN = SM_D + 4;             // 1
constexpr int SM_CNT = SM_DEN + 1;
constexpr size_t SM_BYTES = ((size_t)SM_CNT * 4 + 255) & ~(size_t)255;

struct Params {
  const float *residual, *text, *Wih_a, *Whh_a, *bih_a, *bhh_a,
      *Wq, *Wk, *Wv, *v_w, *Wih0, *Whh0, *bih0, *bhh0,
      *Wih1, *Whh1, *bih1, *bhh1, *D0w, *D0b, *D1w, *D1b,
      *conv_w, *conv_b, *gate_w, *gate_b;
  float* out;
  float* ws;
};

__device__ __forceinline__ float sigm(float x) { return 1.0f / (1.0f + __expf(-x)); }
__device__ __forceinline__ float ftanh(float x) {
  x = fminf(15.f, fmaxf(-15.f, x));
  float e = __expf(2.f * x);
  return (e - 1.f) / (e + 1.f);
}

// Coherent (agent-scope, cache-bypassing) accessors for mutable ws data.
__device__ __forceinline__ float aload(const float* p) {
  return __hip_atomic_load(p, __ATOMIC_RELAXED, __HIP_MEMORY_SCOPE_AGENT);
}
__device__ __forceinline__ void astore(float* p, float v) {
  __hip_atomic_store(p, v, __ATOMIC_RELAXED, __HIP_MEMORY_SCOPE_AGENT);
}

// Fence-light grid barrier (no L2 wb/inv): drain own vmem, then hierarchical
// relaxed-atomic arrival tree (16 padded leaves -> root -> epoch), poll epoch.
__device__ __forceinline__ void gbar(unsigned* bar, unsigned k) {
  asm volatile("s_waitcnt vmcnt(0)" ::: "memory");
  __syncthreads();
  if (threadIdx.x == 0) {
    unsigned* leaf = bar + (blockIdx.x & 15) * 32;  // 128B apart
    unsigned o = __hip_atomic_fetch_add(leaf, 1u, __ATOMIC_RELAXED,
                                        __HIP_MEMORY_SCOPE_AGENT);
    if ((o & 15) == 15) {  // 16 arrivals per leaf
      unsigned r = __hip_atomic_fetch_add(bar + 512, 1u, __ATOMIC_RELAXED,
                                          __HIP_MEMORY_SCOPE_AGENT);
      if ((r & 15) == 15)
        __hip_atomic_fetch_add(bar + 544, 1u, __ATOMIC_RELAXED,
                               __HIP_MEMORY_SCOPE_AGENT);
    }
    while (__hip_atomic_load(bar + 544, __ATOMIC_RELAXED,
                             __HIP_MEMORY_SCOPE_AGENT) < k)
      __builtin_amdgcn_s_sleep(1);
  }
  __syncthreads();
}

__device__ __forceinline__ float red64(float s) {
#pragma unroll
  for (int off = 32; off; off >>= 1) s += __shfl_xor(s, off, 64);
  return s;
}

// partial dot of 1024-length row held in 4 pinned float4s vs x (LDS)
__device__ __forceinline__ float dot16pin(float4 w0, float4 w1, float4 w2,
                                          float4 w3, const float* x, int lane) {
  const float4* x4 = (const float4*)x;
  float4 b0 = x4[lane], b1 = x4[lane + 64], b2 = x4[lane + 128],
         b3 = x4[lane + 192];
  float s0 = w0.x * b0.x, s1 = w1.x * b1.x;
  s0 = fmaf(w0.y, b0.y, s0); s1 = fmaf(w1.y, b1.y, s1);
  s0 = fmaf(w0.z, b0.z, s0); s1 = fmaf(w1.z, b1.z, s1);
  s0 = fmaf(w0.w, b0.w, s0); s1 = fmaf(w1.w, b1.w, s1);
  s0 = fmaf(w2.x, b2.x, s0); s1 = fmaf(w3.x, b3.x, s1);
  s0 = fmaf(w2.y, b2.y, s0); s1 = fmaf(w3.y, b3.y, s1);
  s0 = fmaf(w2.z, b2.z, s0); s1 = fmaf(w3.z, b3.z, s1);
  s0 = fmaf(w2.w, b2.w, s0); s1 = fmaf(w3.w, b3.w, s1);
  return s0 + s1;
}

// partial dot of 1024-length row (any address space) vs x
__device__ __forceinline__ float dot16load(const float* w, const float* x,
                                           int lane) {
  const float4* w4 = (const float4*)w;
  const float4* x4 = (const float4*)x;
  float4 a0 = w4[lane], a1 = w4[lane + 64], a2 = w4[lane + 128],
         a3 = w4[lane + 192];
  float4 b0 = x4[lane], b1 = x4[lane + 64], b2 = x4[lane + 128],
         b3 = x4[lane + 192];
  float s0 = a0.x * b0.x, s1 = a1.x * b1.x;
  s0 = fmaf(a0.y, b0.y, s0); s1 = fmaf(a1.y, b1.y, s1);
  s0 = fmaf(a0.z, b0.z, s0); s1 = fmaf(a1.z, b1.z, s1);
  s0 = fmaf(a0.w, b0.w, s0); s1 = fmaf(a1.w, b1.w, s1);
  s0 = fmaf(a2.x, b2.x, s0); s1 = fmaf(a3.x, b3.x, s1);
  s0 = fmaf(a2.y, b2.y, s0); s1 = fmaf(a3.y, b3.y, s1);
  s0 = fmaf(a2.z, b2.z, s0); s1 = fmaf(a3.z, b3.z, s1);
  s0 = fmaf(a2.w, b2.w, s0); s1 = fmaf(a3.w, b3.w, s1);
  return s0 + s1;
}

__device__ __forceinline__ float wave_dot(const float* __restrict__ w,
                                          const float* __restrict__ x,
                                          int n4, int lane) {
  float s = 0.f;
  const float4* w4 = (const float4*)w;
  const float4* x4 = (const float4*)x;
  for (int i = lane; i < n4; i += 64) {
    float4 a = w4[i];
    float4 b = x4[i];
    s = fmaf(a.x, b.x, s);
    s = fmaf(a.y, b.y, s);
    s = fmaf(a.z, b.z, s);
    s = fmaf(a.w, b.w, s);
  }
  return red64(s);
}

__global__ void __launch_bounds__(NTHR, 4) ar_kernel(Params p) {
  const int b = blockIdx.x;
  const int tid = threadIdx.x;
  const int wave = tid >> 6;   // 0..15
  const int lane = tid & 63;
  const int sg = wave >> 2;    // element subgroup 0..3
  const int wg = wave & 3;     // gate / k-chunk within subgroup
  const int gw = b * 16 + wave;  // global wave 0..4095

  float* ws = p.ws;
  float* Kw = ws + WS_K;
  float* Vw = ws + WS_V;
  float* hbuf = ws + WS_HBUF;
  float* h0buf = ws + WS_H0BUF;
  float* h1buf = ws + WS_H1BUF;
  float* qv = ws + WS_Q;
  float* ctxa = ws + WS_CTX;
  float* den = ws + WS_DEN;
  float* ghp = ws + WS_GH;
  float* dec = ws + WS_DEC;
  float* a0 = ws + WS_A0;
  unsigned* bar = (unsigned*)(ws + WS_BAR);

  extern __shared__ __align__(16) float smem[];
  float* s_w0 = smem + SM_W0;
  float* s_h = smem + SM_H;
  float* s_h0 = smem + SM_H0;
  float* s_h1 = smem + SM_H1;
  float* s_att = smem + SM_ATT;
  float* s_k = smem + SM_K;
  float* s_v = smem + SM_V;
  float* s_vw = smem + SM_VW;
  float* s_out = smem + SM_OUT;
  float* s_dec = smem + SM_DEC;
  float* s_red = smem + SM_RED;
  float* s_d = smem + SM_D;
  float* s_den = smem + SM_DEN;

  const int e = 4 * b + sg;
  const int grow = e + wg * H;  // row for phases A(gate), B, D, E

  // ---- pin invariant weight rows in registers (constant across all t) ----
  const float4* WA = (const float4*)(p.Whh_a + (size_t)grow * H);
  float4 wa0 = WA[lane], wa1 = WA[lane + 64], wa2 = WA[lane + 128],
         wa3 = WA[lane + 192];
  const float4* W0 = (const float4*)(p.Whh0 + (size_t)grow * H);
  float4 w00 = W0[lane], w01 = W0[lane + 64], w02 = W0[lane + 128],
         w03 = W0[lane + 192];
  const float4* W1 = (const float4*)(p.Whh1 + (size_t)grow * H);
  float4 w10 = W1[lane], w11 = W1[lane + 64], w12 = W1[lane + 128],
         w13 = W1[lane + 192];
  const float4* WI = (const float4*)(p.Wih1 + (size_t)grow * H);
  float4 wi0 = WI[lane], wi1 = WI[lane + 64], wi2 = WI[lane + 128],
         wi3 = WI[lane + 192];
  float4 wma = make_float4(0.f, 0.f, 0.f, 0.f);
  if (lane < MEL / 4)
    wma = ((const float4*)(p.Wih_a + (size_t)grow * MEL))[lane];
  float4 wf = ((const float4*)(p.D0w + (size_t)e * H))[wg * 64 + lane];
  float4 wgd = ((const float4*)(p.D1w + (size_t)e * H))[wg * 64 + lane];
  float4 wcv = make_float4(0.f, 0.f, 0.f, 0.f);
  if (tid < 2 * MEL) wcv = ((const float4*)(p.conv_w + (size_t)tid * H))[b];
  // Wq row (waves 0..639) or gate_w[:1024] (block 40 wave 0) pinned:
  const float* xsrc = nullptr;
  if (gw < ATT) xsrc = p.Wq + (size_t)gw * H;
  else if (gw == ATT) xsrc = p.gate_w;
  float4 wx0 = make_float4(0.f, 0.f, 0.f, 0.f), wx1 = wx0, wx2 = wx0, wx3 = wx0;
  if (xsrc) {
    const float4* X = (const float4*)xsrc;
    wx0 = X[lane]; wx1 = X[lane + 64]; wx2 = X[lane + 128]; wx3 = X[lane + 192];
  }
  const float ba = p.bih_a[grow] + p.bhh_a[grow];
  const float b0s = p.bih0[grow] + p.bhh0[grow];
  const float b1s = p.bih1[grow] + p.bhh1[grow];

  // ---- stage this block's Wih0 rows (grow-mapped) into LDS ----
  {
    const float4* src = (const float4*)(p.Wih0 + (size_t)grow * DIN);
    float4* dst = (float4*)(s_w0 + wave * DIN);
    for (int i = lane; i < DIN / 4; i += 64) dst[i] = src[i];
  }
  for (int i = tid; i < ATT; i += NTHR) s_vw[i] = p.v_w[i];

  // block-private LSTM cell states (element 4b+tid, threads 0..3 only)
  float c_reg = 0.f, c0_reg = 0.f, c1_reg = 0.f;
  // per-wave scalars carried between phases (same wave produces & consumes)
  float u0_reg = 0.f, u1_reg = 0.f, w0h_reg = 0.f;

  unsigned bk = 0;

  // ---------------- init: zero state, precompute K,V (atomic stores) -------
  if (b == 0) {
    for (int i = tid; i < 6 * H; i += NTHR) astore(&hbuf[i], 0.f);
  }
  for (int idx = gw; idx < 2 * TTXT * ATT; idx += NBLK * 16) {
    int isV = idx >= TTXT * ATT;
    int rem = isV ? idx - TTXT * ATT : idx;
    int j = rem / ATT;
    int a = rem - j * ATT;
    const float* wrow = (isV ? p.Wv : p.Wk) + a * TXTD;
    float s = wave_dot(wrow, p.text + j * TXTD, TXTD / 4, lane);
    if (lane == 0) astore(&(isV ? Vw : Kw)[j * ATT + a], s);
  }
  gbar(bar, ++bk);
  // stage this block's K/V row to LDS (attention blocks only)
  if (b < TTXT) {
    for (int i = tid; i < ATT; i += NTHR) {
      s_k[i] = aload(&Kw[b * ATT + i]);
      s_v[i] = aload(&Vw[b * ATT + i]);
    }
  }

  // ---------------- main sequential loop ----------------
  for (int t = 0; t < T; ++t) {
    const float* h_old = hbuf + (t & 1) * H;
    float* h_new = hbuf + ((t + 1) & 1) * H;
    const float* h0_old = h0buf + (t & 1) * H;
    float* h0_new = h0buf + ((t + 1) & 1) * H;
    const float* h1_old = h1buf + (t & 1) * H;
    float* h1_new = h1buf + ((t + 1) & 1) * H;

    // ---- Phase A: stage prev state; prev output; gates + u0/u1 (pinned) ----
    s_h[tid] = aload(h_old + tid);
    s_h0[tid] = aload(h0_old + tid);
    s_h1[tid] = aload(h1_old + tid);
    if (tid < 2 * MEL) s_dec[tid] = aload(dec + tid);
    __syncthreads();
    if (tid < MEL) {
      float o = 0.f;
      if (t != 0) {
        float ls = s_dec[tid] + p.conv_b[tid];
        float bb = s_dec[MEL + tid] + p.conv_b[MEL + tid];
        float r = p.residual[(T - t) * MEL + tid];
        o = (r - bb) * __expf(-ls);
        if (b == 0) p.out[(T - t) * MEL + tid] = o;
      }
      s_out[tid] = o;
    }
    __syncthreads();
    {
      float pa = dot16pin(wa0, wa1, wa2, wa3, s_h, lane);
      if (lane < MEL / 4) {
        float4 bm = ((const float4*)s_out)[lane];
        pa = fmaf(wma.x, bm.x, pa);
        pa = fmaf(wma.y, bm.y, pa);
        pa = fmaf(wma.z, bm.z, pa);
        pa = fmaf(wma.w, bm.w, pa);
      }
      float pu0 = dot16pin(w00, w01, w02, w03, s_h0, lane);
      float pu1 = dot16pin(w10, w11, w12, w13, s_h1, lane);
      pa = red64(pa);
      u0_reg = red64(pu0);  // kept in-wave for phase D
      u1_reg = red64(pu1);  // kept in-wave for phase E
      if (lane == 0) s_red[wave] = pa + ba;
      __syncthreads();
      if (tid < 4) {
        int ee = 4 * b + tid;
        float gi = s_red[tid * 4 + 0], gf = s_red[tid * 4 + 1];
        float gg = s_red[tid * 4 + 2], go = s_red[tid * 4 + 3];
        float c2 = sigm(gf) * c_reg + sigm(gi) * ftanh(gg);
        c_reg = c2;
        astore(&h_new[ee], sigm(go) * ftanh(c2));
      }
    }
    gbar(bar, ++bk);

    // ---- Phase B: stage h_new; w0h from LDS weights; qv/gate (pinned) ------
    s_h[tid] = aload(h_new + tid);
    __syncthreads();
    {
      float s0 = dot16load(s_w0 + wave * DIN, s_h, lane);
      w0h_reg = red64(s0);  // kept in-wave for phase D
      if (xsrc) {
        float q = dot16pin(wx0, wx1, wx2, wx3, s_h, lane);
        q = red64(q);
        if (lane == 0) {
          if (gw < ATT) astore(&qv[gw], q);
          else astore(&ghp[0], q);
        }
      }
      if (b == NBLK - 1) {
        for (int i = tid; i < ATT; i += NTHR) astore(&ctxa[i], 0.f);
        if (tid == 0) astore(den, 0.f);
        for (int i = tid; i < 2 * MEL; i += NTHR) astore(&dec[i], 0.f);
      }
    }
    gbar(bar, ++bk);

    // ---- Phase C: scores -> exp -> ctx accumulation (fixed-shift softmax) --
    if (b < TTXT) {
      if (tid < ATT) s_att[tid] = aload(&qv[tid]);
      __syncthreads();
      float sp = 0.f;
      for (int i = tid; i < ATT; i += NTHR)
        sp += ftanh(s_att[i] + s_k[i]) * s_vw[i];
      sp = red64(sp);
      if (lane == 0) s_red[wave] = sp;
      __syncthreads();
      float sc = 0.f;
#pragma unroll
      for (int k = 0; k < 16; ++k) sc += s_red[k];
      float pj = __expf(sc - 16.f);  // scores bounded ~±11, shift is safe
      for (int i = tid; i < ATT; i += NTHR)
        atomicAdd(&ctxa[i], pj * s_v[i]);
      if (tid == 0) atomicAdd(den, pj);
    }
    gbar(bar, ++bk);

    // ---- Phase D: dec LSTM0: ctx part from LDS weights (unnorm, *inv) ------
    {
      if (tid < ATT) s_att[tid] = aload(&ctxa[tid]);
      if (tid == NTHR - 1) s_den[0] = aload(den);
      __syncthreads();
      const float4* W4 = (const float4*)(s_w0 + wave * DIN + H);
      const float4* X4 = (const float4*)s_att;
      float4 a_ = W4[lane], b_ = X4[lane];
      float4 a2 = W4[lane + 64], b2 = X4[lane + 64];
      float s = a_.x * b_.x;
      s = fmaf(a_.y, b_.y, s); s = fmaf(a_.z, b_.z, s); s = fmaf(a_.w, b_.w, s);
      s = fmaf(a2.x, b2.x, s); s = fmaf(a2.y, b2.y, s);
      s = fmaf(a2.z, b2.z, s); s = fmaf(a2.w, b2.w, s);
      if (lane < 32) {
        float4 a3 = W4[128 + lane], b3 = X4[128 + lane];
        s = fmaf(a3.x, b3.x, s); s = fmaf(a3.y, b3.y, s);
        s = fmaf(a3.z, b3.z, s); s = fmaf(a3.w, b3.w, s);
      }
      s = red64(s);
      float inv = 1.f / s_den[0];
      if (lane == 0) s_red[wave] = s * inv + w0h_reg + u0_reg + b0s;
      if (b == 0 && wave == 15) {
        float gc = wave_dot(p.gate_w + H, s_att, ATT / 4, lane);
        if (lane == 0) {
          float gh = aload(&ghp[0]);
          p.out[T * MEL + t] = sigm(gh + gc * inv + p.gate_b[0]);
        }
      }
      __syncthreads();
      if (tid < 4) {
        int ee = 4 * b + tid;
        float gi = s_red[tid * 4 + 0], gf = s_red[tid * 4 + 1];
        float gg = s_red[tid * 4 + 2], go = s_red[tid * 4 + 3];
        float c2 = sigm(gf) * c0_reg + sigm(gi) * ftanh(gg);
        c0_reg = c2;
        astore(&h0_new[ee], sigm(go) * ftanh(c2));
      }
    }
    gbar(bar, ++bk);

    // ---- Phase E: dec LSTM1 (pinned Wih1 row) ----
    s_h[tid] = aload(h0_new + tid);
    __syncthreads();
    {
      float pe = dot16pin(wi0, wi1, wi2, wi3, s_h, lane);
      pe = red64(pe);
      if (lane == 0) s_red[wave] = pe + u1_reg + b1s;
      __syncthreads();
      if (tid < 4) {
        int ee = 4 * b + tid;
        float gi = s_red[tid * 4 + 0], gf = s_red[tid * 4 + 1];
        float gg = s_red[tid * 4 + 2], go = s_red[tid * 4 + 3];
        float c2 = sigm(gf) * c1_reg + sigm(gi) * ftanh(gg);
        c1_reg = c2;
        astore(&h1_new[ee], sigm(go) * ftanh(c2));
      }
    }
    gbar(bar, ++bk);

    // ---- Phase F: a0 = tanh(D0w@h1 + D0b); pinned D0w f4, k-split 4 waves --
    s_h[tid] = aload(h1_new + tid);
    __syncthreads();
    {
      float4 x = ((const float4*)s_h)[wg * 64 + lane];
      float s = wf.x * x.x;
      s = fmaf(wf.y, x.y, s); s = fmaf(wf.z, x.z, s); s = fmaf(wf.w, x.w, s);
      s = red64(s);
      if (lane == 0) s_red[wave] = s;
      __syncthreads();
      if (tid < 4) {
        int r2 = 4 * b + tid;
        float tot = s_red[tid * 4] + s_red[tid * 4 + 1] + s_red[tid * 4 + 2] +
                    s_red[tid * 4 + 3];
        astore(&a0[r2], ftanh(tot + p.D0b[r2]));
      }
    }
    gbar(bar, ++bk);

    // ---- Phase G: d = tanh(D1w@a0 + D1b); conv partial into dec ----
    s_h[tid] = aload(a0 + tid);
    __syncthreads();
    {
      float4 x = ((const float4*)s_h)[wg * 64 + lane];
      float s = wgd.x * x.x;
      s = fmaf(wgd.y, x.y, s); s = fmaf(wgd.z, x.z, s); s = fmaf(wgd.w, x.w, s);
      s = red64(s);
      if (lane == 0) s_red[wave] = s;
      __syncthreads();
      if (tid < 4) {
        int r2 = 4 * b + tid;
        float tot = s_red[tid * 4] + s_red[tid * 4 + 1] + s_red[tid * 4 + 2] +
                    s_red[tid * 4 + 3];
        s_d[tid] = ftanh(tot + p.D1b[r2]);
      }
      __syncthreads();
      if (tid < 2 * MEL) {
        float acc = wcv.x * s_d[0];
        acc = fmaf(wcv.y, s_d[1], acc);
        acc = fmaf(wcv.z, s_d[2], acc);
        acc = fmaf(wcv.w, s_d[3], acc);
        atomicAdd(&dec[tid], acc);
      }
    }
    gbar(bar, ++bk);
  }

  // ---- epilogue: output for t = T-1 (total[0]) ----
  if (b == 0 && tid < MEL) {
    float ls = aload(&dec[tid]) + p.conv_b[tid];
    float bb = aload(&dec[MEL + tid]) + p.conv_b[MEL + tid];
    float r = p.residual[tid];
    p.out[tid] = (r - bb) * __expf(-ls);
  }
}

extern "C" void kernel_launch(void* const* d_in, const int* in_sizes, int n_in,
                              void* d_out, int out_size, void* d_ws, size_t ws_size,
                              hipStream_t stream) {
  Params hp;
  hp.residual = (const float*)d_in[0];
  hp.text = (const float*)d_in[1];
  hp.Wih_a = (const float*)d_in[2];
  hp.Whh_a = (const float*)d_in[3];
  hp.bih_a = (const float*)d_in[4];
  hp.bhh_a = (const float*)d_in[5];
  hp.Wq = (const float*)d_in[6];
  hp.Wk = (const float*)d_in[7];
  hp.Wv = (const float*)d_in[8];
  hp.v_w = (const float*)d_in[9];
  hp.Wih0 = (const float*)d_in[10];
  hp.Whh0 = (const float*)d_in[11];
  hp.bih0 = (const float*)d_in[12];
  hp.bhh0 = (const float*)d_in[13];
  hp.Wih1 = (const float*)d_in[14];
  hp.Whh1 = (const float*)d_in[15];
  hp.bih1 = (const float*)d_in[16];
  hp.bhh1 = (const float*)d_in[17];
  hp.D0w = (const float*)d_in[18];
  hp.D0b = (const float*)d_in[19];
  hp.D1w = (const float*)d_in[20];
  hp.D1b = (const float*)d_in[21];
  hp.conv_w = (const float*)d_in[22];
  hp.conv_b = (const float*)d_in[23];
  hp.gate_w = (const float*)d_in[24];
  hp.gate_b = (const float*)d_in[25];
  hp.out = (float*)d_out;
  hp.ws = (float*)d_ws;

  // barrier counters must be 0 before the kernel runs (ws is poisoned 0xAA
  // before every timed launch; memset node is graph-capturable).
  hipMemsetAsync((char*)d_ws + (size_t)WS_BAR * sizeof(float), 0, 4096, stream);

  void* args[] = {&hp};
  hipLaunchCooperativeKernel((void*)ar_kernel, dim3(NBLK), dim3(NTHR), args,
                             (uint32_t)SM_BYTES, stream);
}